// Round 1
// baseline (1939.466 us; speedup 1.0000x reference)
//
#include <hip/hip_runtime.h>
#include <hip/hip_bf16.h>

// ---------------------------------------------------------------------------
// DeepSGC: 6 hops of D^{-1/2} A D^{-1/2} SpMM (pull-style over CSR built
// per-call) + 3 dense layers (fp32 vector, W staged in LDS).
// ---------------------------------------------------------------------------

__global__ void __launch_bounds__(256) deg_kernel(const int* __restrict__ dst,
                                                  int* __restrict__ deg, int E) {
    int stride = gridDim.x * blockDim.x;
    for (int e = blockIdx.x * blockDim.x + threadIdx.x; e < E; e += stride) {
        atomicAdd(&deg[dst[e]], 1);
    }
}

__global__ void __launch_bounds__(256) norm_kernel(const int* __restrict__ deg,
                                                   float* __restrict__ norm, int n) {
    int i = blockIdx.x * blockDim.x + threadIdx.x;
    if (i < n) {
        int d = deg[i];
        float df = (float)(d < 1 ? 1 : d);
        norm[i] = rsqrtf(df);
    }
}

// Single-block hierarchical exclusive scan (wave shfl scan + cross-wave LDS).
__global__ void __launch_bounds__(1024) scan_kernel(const int* __restrict__ deg,
                                                    int* __restrict__ row_ptr, int n) {
    __shared__ int wsum[16];
    __shared__ int carry_s;
    int t = threadIdx.x, lane = t & 63, w = t >> 6;
    if (t == 0) carry_s = 0;
    __syncthreads();
    for (int base = 0; base < n; base += 1024) {
        int i = base + t;
        int v = (i < n) ? deg[i] : 0;
        int x = v;
        #pragma unroll
        for (int off = 1; off < 64; off <<= 1) {
            int y = __shfl_up(x, off, 64);
            if (lane >= off) x += y;
        }
        if (lane == 63) wsum[w] = x;
        __syncthreads();
        if (w == 0) {
            int s = (lane < 16) ? wsum[lane] : 0;
            int sx = s;
            #pragma unroll
            for (int off = 1; off < 16; off <<= 1) {
                int y = __shfl_up(sx, off, 64);
                if (lane >= off) sx += y;
            }
            if (lane < 16) wsum[lane] = sx - s;  // exclusive wave offset
        }
        __syncthreads();
        int excl = x - v + wsum[w] + carry_s;
        if (i < n) row_ptr[i] = excl;
        __syncthreads();
        if (t == 1023) carry_s = carry_s + wsum[15] + x;  // x = wave15 inclusive sum
        __syncthreads();
    }
    if (t == 0) row_ptr[n] = carry_s;
}

__global__ void __launch_bounds__(256) fill_kernel(const int* __restrict__ src,
                                                   const int* __restrict__ dst,
                                                   const int* __restrict__ row_ptr,
                                                   int* __restrict__ cnt,
                                                   int* __restrict__ col, int E) {
    int stride = gridDim.x * blockDim.x;
    for (int e = blockIdx.x * blockDim.x + threadIdx.x; e < E; e += stride) {
        int d = dst[e];
        int p = row_ptr[d] + atomicAdd(&cnt[d], 1);
        col[p] = src[e];
    }
}

// Pull SpMM: out[v] = norm[v] * sum_{u in N_in(v)} h[u] * norm[u]
// One wave per node; lane owns a float2 (128 feats = 64 lanes x 2).
__global__ void __launch_bounds__(256) spmm_kernel(const float2* __restrict__ hin,
                                                   float2* __restrict__ hout,
                                                   const int* __restrict__ row_ptr,
                                                   const int* __restrict__ col,
                                                   const float* __restrict__ norm,
                                                   int n) {
    int wid = (blockIdx.x * blockDim.x + threadIdx.x) >> 6;
    int lane = threadIdx.x & 63;
    if (wid >= n) return;
    int beg = row_ptr[wid];
    int end = row_ptr[wid + 1];
    float2 acc; acc.x = 0.f; acc.y = 0.f;
    int e = beg;
    for (; e + 2 <= end; e += 2) {
        int u0 = col[e], u1 = col[e + 1];
        float w0 = norm[u0], w1 = norm[u1];
        float2 x0 = hin[(size_t)u0 * 64 + lane];
        float2 x1 = hin[(size_t)u1 * 64 + lane];
        acc.x += x0.x * w0; acc.y += x0.y * w0;
        acc.x += x1.x * w1; acc.y += x1.y * w1;
    }
    if (e < end) {
        int u0 = col[e];
        float w0 = norm[u0];
        float2 x0 = hin[(size_t)u0 * 64 + lane];
        acc.x += x0.x * w0; acc.y += x0.y * w0;
    }
    float nv = norm[wid];
    float2 o; o.x = acc.x * nv; o.y = acc.y * nv;
    hout[(size_t)wid * 64 + lane] = o;
}

// Dense 128->128 (+bias, optional relu). W staged in LDS (64 KiB), wave/row,
// lane owns cols (lane, lane+64).
template <int RELU>
__global__ void __launch_bounds__(256) gemm128_kernel(const float* __restrict__ A,
                                                      const float* __restrict__ W,
                                                      const float* __restrict__ bias,
                                                      float* __restrict__ out, int n) {
    __shared__ float Wl[128 * 128];  // 64 KiB
    for (int i = threadIdx.x; i < 128 * 128; i += 256) Wl[i] = W[i];
    __syncthreads();
    int lane = threadIdx.x & 63;
    int wid = (blockIdx.x * blockDim.x + threadIdx.x) >> 6;
    int nwaves = (gridDim.x * blockDim.x) >> 6;
    float b0 = bias[lane];
    float b1 = bias[lane + 64];
    for (int r = wid; r < n; r += nwaves) {
        const float* a = A + (size_t)r * 128;
        float acc0 = 0.f, acc1 = 0.f;
        for (int k = 0; k < 128; k += 4) {
            float4 av = *reinterpret_cast<const float4*>(a + k);
            float aw;
            aw = av.x; acc0 += aw * Wl[(k + 0) * 128 + lane]; acc1 += aw * Wl[(k + 0) * 128 + lane + 64];
            aw = av.y; acc0 += aw * Wl[(k + 1) * 128 + lane]; acc1 += aw * Wl[(k + 1) * 128 + lane + 64];
            aw = av.z; acc0 += aw * Wl[(k + 2) * 128 + lane]; acc1 += aw * Wl[(k + 2) * 128 + lane + 64];
            aw = av.w; acc0 += aw * Wl[(k + 3) * 128 + lane]; acc1 += aw * Wl[(k + 3) * 128 + lane + 64];
        }
        acc0 += b0; acc1 += b1;
        if (RELU) { acc0 = fmaxf(acc0, 0.f); acc1 = fmaxf(acc1, 0.f); }
        out[(size_t)r * 128 + lane] = acc0;
        out[(size_t)r * 128 + lane + 64] = acc1;
    }
}

// Dense 128->40 (+bias, no relu). W3 in LDS (20 KiB). lane<40 active per row.
__global__ void __launch_bounds__(256) gemm40_kernel(const float* __restrict__ A,
                                                     const float* __restrict__ W,
                                                     const float* __restrict__ bias,
                                                     float* __restrict__ out, int n) {
    __shared__ float Wl[128 * 40];  // 20 KiB
    for (int i = threadIdx.x; i < 128 * 40; i += 256) Wl[i] = W[i];
    __syncthreads();
    int lane = threadIdx.x & 63;
    int wid = (blockIdx.x * blockDim.x + threadIdx.x) >> 6;
    int nwaves = (gridDim.x * blockDim.x) >> 6;
    float b0 = (lane < 40) ? bias[lane] : 0.f;
    for (int r = wid; r < n; r += nwaves) {
        const float* a = A + (size_t)r * 128;
        float acc = 0.f;
        for (int k = 0; k < 128; k += 4) {
            float4 av = *reinterpret_cast<const float4*>(a + k);
            if (lane < 40) {
                acc += av.x * Wl[(k + 0) * 40 + lane];
                acc += av.y * Wl[(k + 1) * 40 + lane];
                acc += av.z * Wl[(k + 2) * 40 + lane];
                acc += av.w * Wl[(k + 3) * 40 + lane];
            }
        }
        if (lane < 40) out[(size_t)r * 40 + lane] = acc + b0;
    }
}

extern "C" void kernel_launch(void* const* d_in, const int* in_sizes, int n_in,
                              void* d_out, int out_size, void* d_ws, size_t ws_size,
                              hipStream_t stream) {
    const float* features = (const float*)d_in[0];
    const int*   src      = (const int*)d_in[1];
    const int*   dst      = (const int*)d_in[2];
    const float* W1 = (const float*)d_in[3];
    const float* b1 = (const float*)d_in[4];
    const float* W2 = (const float*)d_in[5];
    const float* b2 = (const float*)d_in[6];
    const float* W3 = (const float*)d_in[7];
    const float* b3 = (const float*)d_in[8];
    float* out = (float*)d_out;

    const int N = in_sizes[0] / 128;
    const int E = in_sizes[1];

    // workspace layout (512B-aligned slots)
    char* ws = (char*)d_ws;
    size_t off = 0;
    auto alloc = [&](size_t bytes) -> void* {
        void* p = ws + off;
        off += (bytes + 511) & ~(size_t)511;
        return p;
    };
    float* bufA   = (float*)alloc((size_t)N * 128 * sizeof(float));
    float* bufB   = (float*)alloc((size_t)N * 128 * sizeof(float));
    int*   col    = (int*)alloc((size_t)E * sizeof(int));
    int*   deg    = (int*)alloc((size_t)N * sizeof(int));
    int*   cnt    = (int*)alloc((size_t)N * sizeof(int));
    int*   rowptr = (int*)alloc((size_t)(N + 1) * sizeof(int));
    float* norm   = (float*)alloc((size_t)N * sizeof(float));

    // --- build CSR (rows = dst) ---
    hipMemsetAsync(deg, 0, (size_t)N * sizeof(int), stream);
    hipMemsetAsync(cnt, 0, (size_t)N * sizeof(int), stream);
    deg_kernel<<<1024, 256, 0, stream>>>(dst, deg, E);
    norm_kernel<<<(N + 255) / 256, 256, 0, stream>>>(deg, norm, N);
    scan_kernel<<<1, 1024, 0, stream>>>(deg, rowptr, N);
    fill_kernel<<<1024, 256, 0, stream>>>(src, dst, rowptr, cnt, col, E);

    const int spmm_blocks = (N * 64 + 255) / 256;  // one wave per node
    const int gemm_blocks = 1024;

    // layer 1: 2 hops + W1 + relu
    spmm_kernel<<<spmm_blocks, 256, 0, stream>>>((const float2*)features, (float2*)bufA, rowptr, col, norm, N);
    spmm_kernel<<<spmm_blocks, 256, 0, stream>>>((const float2*)bufA, (float2*)bufB, rowptr, col, norm, N);
    gemm128_kernel<1><<<gemm_blocks, 256, 0, stream>>>(bufB, W1, b1, bufA, N);

    // layer 2: 2 hops + W2 + relu
    spmm_kernel<<<spmm_blocks, 256, 0, stream>>>((const float2*)bufA, (float2*)bufB, rowptr, col, norm, N);
    spmm_kernel<<<spmm_blocks, 256, 0, stream>>>((const float2*)bufB, (float2*)bufA, rowptr, col, norm, N);
    gemm128_kernel<1><<<gemm_blocks, 256, 0, stream>>>(bufA, W2, b2, bufB, N);

    // layer 3: 2 hops + W3 (no relu)
    spmm_kernel<<<spmm_blocks, 256, 0, stream>>>((const float2*)bufB, (float2*)bufA, rowptr, col, norm, N);
    spmm_kernel<<<spmm_blocks, 256, 0, stream>>>((const float2*)bufA, (float2*)bufB, rowptr, col, norm, N);
    gemm40_kernel<<<gemm_blocks, 256, 0, stream>>>(bufB, W3, b3, out, N);
}

// Round 2
// 1066.766 us; speedup vs baseline: 1.8181x; 1.8181x over previous
//
#include <hip/hip_runtime.h>
#include <hip/hip_bf16.h>

// ---------------------------------------------------------------------------
// DeepSGC on MI355X:
//   - CSR build (deg/scan/fill) per call
//   - 4 hops of 128-wide pull-SpMM (f32), hop 2/4 emit split-bf16 (hi+lo)
//   - dense 128x128 layers via 3x bf16 MFMA (split-precision, ~fp32 accurate)
//   - layer-3 reorder: project to 40 feats FIRST, then 2 hops at 40-wide
// ---------------------------------------------------------------------------

typedef __attribute__((ext_vector_type(8))) short short8v;   // 8 x bf16
typedef __attribute__((ext_vector_type(4))) float f32x4;

__device__ __forceinline__ unsigned short f2bf(float x) {
    unsigned int u = __builtin_bit_cast(unsigned int, x);
    unsigned int r = u + 0x7fffu + ((u >> 16) & 1u);   // RNE
    return (unsigned short)(r >> 16);
}
__device__ __forceinline__ float bf2f(unsigned short h) {
    unsigned int u = ((unsigned int)h) << 16;
    return __builtin_bit_cast(float, u);
}

// ------------------------------- CSR build --------------------------------

__global__ void __launch_bounds__(256) deg_kernel(const int* __restrict__ dst,
                                                  int* __restrict__ deg, int E) {
    int stride = gridDim.x * blockDim.x;
    for (int e = blockIdx.x * blockDim.x + threadIdx.x; e < E; e += stride)
        atomicAdd(&deg[dst[e]], 1);
}

__global__ void __launch_bounds__(256) norm_kernel(const int* __restrict__ deg,
                                                   float* __restrict__ norm, int n) {
    int i = blockIdx.x * blockDim.x + threadIdx.x;
    if (i < n) {
        int d = deg[i];
        norm[i] = rsqrtf((float)(d < 1 ? 1 : d));
    }
}

__global__ void __launch_bounds__(1024) scan_kernel(const int* __restrict__ deg,
                                                    int* __restrict__ row_ptr, int n) {
    __shared__ int wsum[16];
    __shared__ int carry_s;
    int t = threadIdx.x, lane = t & 63, w = t >> 6;
    if (t == 0) carry_s = 0;
    __syncthreads();
    for (int base = 0; base < n; base += 1024) {
        int i = base + t;
        int v = (i < n) ? deg[i] : 0;
        int x = v;
        #pragma unroll
        for (int off = 1; off < 64; off <<= 1) {
            int y = __shfl_up(x, off, 64);
            if (lane >= off) x += y;
        }
        if (lane == 63) wsum[w] = x;
        __syncthreads();
        if (w == 0) {
            int s = (lane < 16) ? wsum[lane] : 0;
            int sx = s;
            #pragma unroll
            for (int off = 1; off < 16; off <<= 1) {
                int y = __shfl_up(sx, off, 64);
                if (lane >= off) sx += y;
            }
            if (lane < 16) wsum[lane] = sx - s;
        }
        __syncthreads();
        int excl = x - v + wsum[w] + carry_s;
        if (i < n) row_ptr[i] = excl;
        __syncthreads();
        if (t == 1023) carry_s = carry_s + wsum[15] + x;
        __syncthreads();
    }
    if (t == 0) row_ptr[n] = carry_s;
}

__global__ void __launch_bounds__(256) fill_kernel(const int* __restrict__ src,
                                                   const int* __restrict__ dst,
                                                   const int* __restrict__ row_ptr,
                                                   int* __restrict__ cnt,
                                                   int* __restrict__ col, int E) {
    int stride = gridDim.x * blockDim.x;
    for (int e = blockIdx.x * blockDim.x + threadIdx.x; e < E; e += stride) {
        int d = dst[e];
        int p = row_ptr[d] + atomicAdd(&cnt[d], 1);
        col[p] = src[e];
    }
}

// ------------------------------- SpMM hops --------------------------------

// 128-wide pull SpMM, f32 -> f32. One wave per node, lane owns a float2.
__global__ void __launch_bounds__(256) spmm_kernel(const float2* __restrict__ hin,
                                                   float2* __restrict__ hout,
                                                   const int* __restrict__ row_ptr,
                                                   const int* __restrict__ col,
                                                   const float* __restrict__ norm,
                                                   int n) {
    int wid = (blockIdx.x * blockDim.x + threadIdx.x) >> 6;
    int lane = threadIdx.x & 63;
    if (wid >= n) return;
    int beg = row_ptr[wid], end = row_ptr[wid + 1];
    float2 acc; acc.x = 0.f; acc.y = 0.f;
    int e = beg;
    for (; e + 2 <= end; e += 2) {
        int u0 = col[e], u1 = col[e + 1];
        float w0 = norm[u0], w1 = norm[u1];
        float2 x0 = hin[(size_t)u0 * 64 + lane];
        float2 x1 = hin[(size_t)u1 * 64 + lane];
        acc.x += x0.x * w0; acc.y += x0.y * w0;
        acc.x += x1.x * w1; acc.y += x1.y * w1;
    }
    if (e < end) {
        int u0 = col[e];
        float w0 = norm[u0];
        float2 x0 = hin[(size_t)u0 * 64 + lane];
        acc.x += x0.x * w0; acc.y += x0.y * w0;
    }
    float nv = norm[wid];
    float2 o; o.x = acc.x * nv; o.y = acc.y * nv;
    hout[(size_t)wid * 64 + lane] = o;
}

// 128-wide pull SpMM, f32 -> split bf16 (hi, lo packed 2-per-uint).
__global__ void __launch_bounds__(256) spmm_split_kernel(const float2* __restrict__ hin,
                                                         unsigned int* __restrict__ hi,
                                                         unsigned int* __restrict__ lo,
                                                         const int* __restrict__ row_ptr,
                                                         const int* __restrict__ col,
                                                         const float* __restrict__ norm,
                                                         int n) {
    int wid = (blockIdx.x * blockDim.x + threadIdx.x) >> 6;
    int lane = threadIdx.x & 63;
    if (wid >= n) return;
    int beg = row_ptr[wid], end = row_ptr[wid + 1];
    float2 acc; acc.x = 0.f; acc.y = 0.f;
    int e = beg;
    for (; e + 2 <= end; e += 2) {
        int u0 = col[e], u1 = col[e + 1];
        float w0 = norm[u0], w1 = norm[u1];
        float2 x0 = hin[(size_t)u0 * 64 + lane];
        float2 x1 = hin[(size_t)u1 * 64 + lane];
        acc.x += x0.x * w0; acc.y += x0.y * w0;
        acc.x += x1.x * w1; acc.y += x1.y * w1;
    }
    if (e < end) {
        int u0 = col[e];
        float w0 = norm[u0];
        float2 x0 = hin[(size_t)u0 * 64 + lane];
        acc.x += x0.x * w0; acc.y += x0.y * w0;
    }
    float nv = norm[wid];
    float ox = acc.x * nv, oy = acc.y * nv;
    unsigned short h0 = f2bf(ox), h1 = f2bf(oy);
    unsigned short l0 = f2bf(ox - bf2f(h0)), l1 = f2bf(oy - bf2f(h1));
    hi[(size_t)wid * 64 + lane] = (unsigned int)h0 | ((unsigned int)h1 << 16);
    lo[(size_t)wid * 64 + lane] = (unsigned int)l0 | ((unsigned int)l1 << 16);
}

// 40-wide pull SpMM (layer-3 hops after the 128->40 projection).
template <int BIAS>
__global__ void __launch_bounds__(256) spmm40_kernel(const float* __restrict__ hin,
                                                     float* __restrict__ hout,
                                                     const int* __restrict__ row_ptr,
                                                     const int* __restrict__ col,
                                                     const float* __restrict__ norm,
                                                     const float* __restrict__ b3,
                                                     int n) {
    int wid = (blockIdx.x * blockDim.x + threadIdx.x) >> 6;
    int lane = threadIdx.x & 63;
    if (wid >= n) return;
    int beg = row_ptr[wid], end = row_ptr[wid + 1];
    bool act = lane < 40;
    float acc = 0.f;
    int e = beg;
    for (; e + 2 <= end; e += 2) {
        int u0 = col[e], u1 = col[e + 1];
        float w0 = norm[u0], w1 = norm[u1];
        if (act) {
            acc += hin[(size_t)u0 * 40 + lane] * w0;
            acc += hin[(size_t)u1 * 40 + lane] * w1;
        }
    }
    if (e < end) {
        int u0 = col[e];
        float w0 = norm[u0];
        if (act) acc += hin[(size_t)u0 * 40 + lane] * w0;
    }
    if (act) {
        float v = acc * norm[wid];
        if (BIAS) v += b3[lane];
        hout[(size_t)wid * 40 + lane] = v;
    }
}

// ------------------------- W fragment preparation --------------------------
// Layout consumed by the MFMA GEMMs: frag f = ks*CF + cf; 64 lanes x 8 bf16.
// Element (f, lane, j) = W[k][c], k = ks*32 + 8*(lane>>4) + j, c = cf*16 + (lane&15).

__global__ void __launch_bounds__(256) wprep_kernel(const float* __restrict__ W,
                                                    short* __restrict__ Wh,
                                                    short* __restrict__ Wl,
                                                    int ncols, int CF, int total) {
    int i = blockIdx.x * blockDim.x + threadIdx.x;
    if (i >= total) return;
    int j = i & 7;
    int lane = (i >> 3) & 63;
    int f = i >> 9;
    int cf = f % CF, ks = f / CF;
    int k = ks * 32 + 8 * (lane >> 4) + j;
    int c = cf * 16 + (lane & 15);
    float v = (c < ncols) ? W[k * ncols + c] : 0.f;
    unsigned short h = f2bf(v);
    unsigned short l = f2bf(v - bf2f(h));
    Wh[i] = (short)h;
    Wl[i] = (short)l;
}

// ------------------------- split-bf16 MFMA GEMMs ---------------------------
// C = (Ahi+Alo) @ (Whi+Wlo) ~= Ahi*Whi + Alo*Whi + Ahi*Wlo  (fp32 accum)
// A: [N,128] bf16 row-major (hi & lo). Wave computes 16 rows x 128 cols.

template <int MODE>  // 0: f32 out (+bias+relu), 1: split-bf16 out (+bias+relu)
__global__ void __launch_bounds__(256) gemm_mfma128(const unsigned short* __restrict__ Ahi,
                                                    const unsigned short* __restrict__ Alo,
                                                    const short8v* __restrict__ Wh,
                                                    const short8v* __restrict__ Wl,
                                                    const float* __restrict__ bias,
                                                    float* __restrict__ Cf,
                                                    unsigned short* __restrict__ Chi,
                                                    unsigned short* __restrict__ Clo,
                                                    int n) {
    int lane = threadIdx.x & 63;
    int wid = threadIdx.x >> 6;
    int r0 = blockIdx.x * 64 + wid * 16;
    if (r0 >= n) return;
    int arow = r0 + (lane & 15);
    if (arow > n - 1) arow = n - 1;
    int kbase = 8 * (lane >> 4);
    f32x4 acc[8];
    #pragma unroll
    for (int i = 0; i < 8; ++i) acc[i] = (f32x4){0.f, 0.f, 0.f, 0.f};
    #pragma unroll
    for (int ks = 0; ks < 4; ++ks) {
        short8v ah = *(const short8v*)(Ahi + (size_t)arow * 128 + ks * 32 + kbase);
        short8v al = *(const short8v*)(Alo + (size_t)arow * 128 + ks * 32 + kbase);
        #pragma unroll
        for (int cf = 0; cf < 8; ++cf) {
            short8v bh = Wh[(ks * 8 + cf) * 64 + lane];
            short8v bl = Wl[(ks * 8 + cf) * 64 + lane];
            acc[cf] = __builtin_amdgcn_mfma_f32_16x16x32_bf16(ah, bh, acc[cf], 0, 0, 0);
            acc[cf] = __builtin_amdgcn_mfma_f32_16x16x32_bf16(al, bh, acc[cf], 0, 0, 0);
            acc[cf] = __builtin_amdgcn_mfma_f32_16x16x32_bf16(ah, bl, acc[cf], 0, 0, 0);
        }
    }
    int rbase = r0 + (lane >> 4) * 4;
    int c0 = lane & 15;
    #pragma unroll
    for (int cf = 0; cf < 8; ++cf) {
        int colc = cf * 16 + c0;
        float b = bias[colc];
        #pragma unroll
        for (int q = 0; q < 4; ++q) {
            int row = rbase + q;
            if (row >= n) continue;
            float v = fmaxf(acc[cf][q] + b, 0.f);
            if (MODE == 0) {
                Cf[(size_t)row * 128 + colc] = v;
            } else {
                unsigned short h = f2bf(v);
                unsigned short l = f2bf(v - bf2f(h));
                Chi[(size_t)row * 128 + colc] = h;
                Clo[(size_t)row * 128 + colc] = l;
            }
        }
    }
}

// 128 -> 40 projection (layer 3, bias added later after the hops).
__global__ void __launch_bounds__(256) gemm_mfma40(const unsigned short* __restrict__ Ahi,
                                                   const unsigned short* __restrict__ Alo,
                                                   const short8v* __restrict__ Wh,
                                                   const short8v* __restrict__ Wl,
                                                   float* __restrict__ Cf, int n) {
    int lane = threadIdx.x & 63;
    int wid = threadIdx.x >> 6;
    int r0 = blockIdx.x * 64 + wid * 16;
    if (r0 >= n) return;
    int arow = r0 + (lane & 15);
    if (arow > n - 1) arow = n - 1;
    int kbase = 8 * (lane >> 4);
    f32x4 acc[3];
    #pragma unroll
    for (int i = 0; i < 3; ++i) acc[i] = (f32x4){0.f, 0.f, 0.f, 0.f};
    #pragma unroll
    for (int ks = 0; ks < 4; ++ks) {
        short8v ah = *(const short8v*)(Ahi + (size_t)arow * 128 + ks * 32 + kbase);
        short8v al = *(const short8v*)(Alo + (size_t)arow * 128 + ks * 32 + kbase);
        #pragma unroll
        for (int cf = 0; cf < 3; ++cf) {
            short8v bh = Wh[(ks * 3 + cf) * 64 + lane];
            short8v bl = Wl[(ks * 3 + cf) * 64 + lane];
            acc[cf] = __builtin_amdgcn_mfma_f32_16x16x32_bf16(ah, bh, acc[cf], 0, 0, 0);
            acc[cf] = __builtin_amdgcn_mfma_f32_16x16x32_bf16(al, bh, acc[cf], 0, 0, 0);
            acc[cf] = __builtin_amdgcn_mfma_f32_16x16x32_bf16(ah, bl, acc[cf], 0, 0, 0);
        }
    }
    int rbase = r0 + (lane >> 4) * 4;
    int c0 = lane & 15;
    #pragma unroll
    for (int cf = 0; cf < 3; ++cf) {
        int colc = cf * 16 + c0;
        if (colc >= 40) continue;
        #pragma unroll
        for (int q = 0; q < 4; ++q) {
            int row = rbase + q;
            if (row >= n) continue;
            Cf[(size_t)row * 40 + colc] = acc[cf][q];
        }
    }
}

// --------------------------------- launch ----------------------------------

extern "C" void kernel_launch(void* const* d_in, const int* in_sizes, int n_in,
                              void* d_out, int out_size, void* d_ws, size_t ws_size,
                              hipStream_t stream) {
    const float* features = (const float*)d_in[0];
    const int*   src      = (const int*)d_in[1];
    const int*   dst      = (const int*)d_in[2];
    const float* W1 = (const float*)d_in[3];
    const float* b1 = (const float*)d_in[4];
    const float* W2 = (const float*)d_in[5];
    const float* b2 = (const float*)d_in[6];
    const float* W3 = (const float*)d_in[7];
    const float* b3 = (const float*)d_in[8];
    float* out = (float*)d_out;

    const int N = in_sizes[0] / 128;
    const int E = in_sizes[1];

    char* ws = (char*)d_ws;
    size_t off = 0;
    auto alloc = [&](size_t bytes) -> void* {
        void* p = ws + off;
        off += (bytes + 511) & ~(size_t)511;
        return p;
    };
    float*          F1   = (float*)alloc((size_t)N * 128 * sizeof(float));
    float*          F2   = (float*)alloc((size_t)N * 128 * sizeof(float));
    unsigned short* Hi   = (unsigned short*)alloc((size_t)N * 128 * sizeof(unsigned short));
    unsigned short* Lo   = (unsigned short*)alloc((size_t)N * 128 * sizeof(unsigned short));
    int*   col    = (int*)alloc((size_t)E * sizeof(int));
    int*   deg    = (int*)alloc((size_t)N * sizeof(int));
    int*   cnt    = (int*)alloc((size_t)N * sizeof(int));
    int*   rowptr = (int*)alloc((size_t)(N + 1) * sizeof(int));
    float* norm   = (float*)alloc((size_t)N * sizeof(float));
    short* W1h = (short*)alloc(16384 * sizeof(short));
    short* W1l = (short*)alloc(16384 * sizeof(short));
    short* W2h = (short*)alloc(16384 * sizeof(short));
    short* W2l = (short*)alloc(16384 * sizeof(short));
    short* W3h = (short*)alloc(6144 * sizeof(short));
    short* W3l = (short*)alloc(6144 * sizeof(short));
    // 40-wide hop buffers alias F2 (free after hop 3 reads it)
    float* G40a = (float*)F2;
    float* G40b = (float*)F2 + (size_t)N * 40;

    // --- CSR build ---
    hipMemsetAsync(deg, 0, (size_t)N * sizeof(int), stream);
    hipMemsetAsync(cnt, 0, (size_t)N * sizeof(int), stream);
    deg_kernel<<<1024, 256, 0, stream>>>(dst, deg, E);
    norm_kernel<<<(N + 255) / 256, 256, 0, stream>>>(deg, norm, N);
    scan_kernel<<<1, 1024, 0, stream>>>(deg, rowptr, N);
    fill_kernel<<<1024, 256, 0, stream>>>(src, dst, rowptr, cnt, col, E);

    // --- W fragment prep ---
    wprep_kernel<<<(16384 + 255) / 256, 256, 0, stream>>>(W1, W1h, W1l, 128, 8, 16384);
    wprep_kernel<<<(16384 + 255) / 256, 256, 0, stream>>>(W2, W2h, W2l, 128, 8, 16384);
    wprep_kernel<<<(6144 + 255) / 256, 256, 0, stream>>>(W3, W3h, W3l, 40, 3, 6144);

    const int spmm_blocks = (N * 64 + 255) / 256;
    const int gemm_blocks = (N + 63) / 64;

    // layer 1: 2 hops + W1 + relu
    spmm_kernel<<<spmm_blocks, 256, 0, stream>>>((const float2*)features, (float2*)F1, rowptr, col, norm, N);
    spmm_split_kernel<<<spmm_blocks, 256, 0, stream>>>((const float2*)F1, (unsigned int*)Hi, (unsigned int*)Lo, rowptr, col, norm, N);
    gemm_mfma128<0><<<gemm_blocks, 256, 0, stream>>>(Hi, Lo, (const short8v*)W1h, (const short8v*)W1l, b1, F2, nullptr, nullptr, N);

    // layer 2: 2 hops + W2 + relu (output emitted as split bf16, consumed by layer-3 GEMM)
    spmm_kernel<<<spmm_blocks, 256, 0, stream>>>((const float2*)F2, (float2*)F1, rowptr, col, norm, N);
    spmm_split_kernel<<<spmm_blocks, 256, 0, stream>>>((const float2*)F1, (unsigned int*)Hi, (unsigned int*)Lo, rowptr, col, norm, N);
    gemm_mfma128<1><<<gemm_blocks, 256, 0, stream>>>(Hi, Lo, (const short8v*)W2h, (const short8v*)W2l, b2, nullptr, Hi, Lo, N);  // in-place: row-disjoint

    // layer 3 (reordered): project 128->40 first, then 2 hops at 40-wide, + b3
    gemm_mfma40<<<gemm_blocks, 256, 0, stream>>>(Hi, Lo, (const short8v*)W3h, (const short8v*)W3l, G40a, N);
    spmm40_kernel<0><<<spmm_blocks, 256, 0, stream>>>(G40a, G40b, rowptr, col, norm, nullptr, N);
    spmm40_kernel<1><<<spmm_blocks, 256, 0, stream>>>(G40b, out, rowptr, col, norm, b3, N);
}

// Round 3
// 1059.189 us; speedup vs baseline: 1.8311x; 1.0072x over previous
//
#include <hip/hip_runtime.h>
#include <hip/hip_bf16.h>

// ---------------------------------------------------------------------------
// DeepSGC on MI355X:
//   - CSR build per call (deg atomics, 3-kernel multi-block scan, fill)
//   - hop pairs folded: k1: z = N^2 A (N.x via gather-scale); k2: y = N A z
//   - 128-wide SpMM: half-wave float4 gather (2 edges/instr), unroll 4
//   - dense layers via 3x bf16 MFMA split-precision (hi+lo)
//   - layer-3 reorder: project 128->40 first, then 2 hops at 40-wide
// ---------------------------------------------------------------------------

typedef __attribute__((ext_vector_type(8))) short short8v;   // 8 x bf16
typedef __attribute__((ext_vector_type(4))) float f32x4;

#define SBLK 128  // scan blocks

__device__ __forceinline__ unsigned short f2bf(float x) {
    unsigned int u = __builtin_bit_cast(unsigned int, x);
    unsigned int r = u + 0x7fffu + ((u >> 16) & 1u);   // RNE
    return (unsigned short)(r >> 16);
}
__device__ __forceinline__ float bf2f(unsigned short h) {
    unsigned int u = ((unsigned int)h) << 16;
    return __builtin_bit_cast(float, u);
}

// ------------------------------- CSR build --------------------------------

__global__ void __launch_bounds__(256) deg_kernel(const int* __restrict__ dst,
                                                  int* __restrict__ deg, int E) {
    int stride = gridDim.x * blockDim.x;
    for (int e = blockIdx.x * blockDim.x + threadIdx.x; e < E; e += stride)
        atomicAdd(&deg[dst[e]], 1);
}

// Per-segment exclusive scan + segment totals + norm computation.
__global__ void __launch_bounds__(256) scanA_kernel(const int* __restrict__ deg,
                                                    int* __restrict__ rowptr,
                                                    int* __restrict__ bsum,
                                                    float* __restrict__ norm,
                                                    int n, int seg) {
    __shared__ int ws[4];
    __shared__ int carry;
    int b = blockIdx.x;
    int start = b * seg;
    int finish = start + seg; if (finish > n) finish = n;
    int t = threadIdx.x, lane = t & 63, w = t >> 6;
    if (t == 0) carry = 0;
    __syncthreads();
    for (int base = start; base < finish; base += 256) {
        int i = base + t;
        int v = 0;
        if (i < finish) {
            v = deg[i];
            norm[i] = rsqrtf((float)(v < 1 ? 1 : v));
        }
        int x = v;
        #pragma unroll
        for (int off = 1; off < 64; off <<= 1) {
            int y = __shfl_up(x, off, 64);
            if (lane >= off) x += y;
        }
        if (lane == 63) ws[w] = x;
        __syncthreads();
        int woff = 0;
        #pragma unroll
        for (int k = 0; k < 4; ++k) if (k < w) woff += ws[k];
        if (i < finish) rowptr[i] = carry + woff + x - v;
        int tot = ws[0] + ws[1] + ws[2] + ws[3];
        __syncthreads();
        if (t == 0) carry += tot;
        __syncthreads();
    }
    if (t == 0) bsum[b] = carry;
}

// Exclusive scan of the SBLK segment totals; bsum[SBLK] = grand total.
__global__ void __launch_bounds__(SBLK) scanB_kernel(int* __restrict__ bsum) {
    __shared__ int tmp[SBLK];
    int t = threadIdx.x;
    int orig = bsum[t];
    tmp[t] = orig;
    __syncthreads();
    for (int off = 1; off < SBLK; off <<= 1) {
        int y = (t >= off) ? tmp[t - off] : 0;
        __syncthreads();
        tmp[t] += y;
        __syncthreads();
    }
    bsum[t] = tmp[t] - orig;
    if (t == SBLK - 1) bsum[SBLK] = tmp[t];
}

// Add segment offsets, zero cnt, write rowptr[n].
__global__ void __launch_bounds__(256) scanC_kernel(int* __restrict__ rowptr,
                                                    const int* __restrict__ bsum,
                                                    int* __restrict__ cnt,
                                                    int n, int seg) {
    int b = blockIdx.x;
    int start = b * seg;
    int finish = start + seg; if (finish > n) finish = n;
    int add = bsum[b];
    for (int i = start + threadIdx.x; i < finish; i += 256) {
        rowptr[i] += add;
        cnt[i] = 0;
    }
    if (b == 0 && threadIdx.x == 0) rowptr[n] = bsum[SBLK];
}

__global__ void __launch_bounds__(256) fill_kernel(const int* __restrict__ src,
                                                   const int* __restrict__ dst,
                                                   const int* __restrict__ row_ptr,
                                                   int* __restrict__ cnt,
                                                   int* __restrict__ col, int E) {
    int stride = gridDim.x * blockDim.x;
    for (int e = blockIdx.x * blockDim.x + threadIdx.x; e < E; e += stride) {
        int d = dst[e];
        int p = row_ptr[d] + atomicAdd(&cnt[d], 1);
        col[p] = src[e];
    }
}

// ------------------------------- SpMM hops --------------------------------
// Half-wave float4 gather: lanes 0-31 handle even edge, 32-63 odd edge.
// Four edges in flight per iteration. Fold halves once at the end.

// k1 of a pair: z = N^2 * A * (N . x)   (gather-scale by norm[src], f32 out)
__global__ void __launch_bounds__(256) spmm128_a(const float4* __restrict__ hin,
                                                 float4* __restrict__ hout,
                                                 const int* __restrict__ rp,
                                                 const int* __restrict__ col,
                                                 const float* __restrict__ norm,
                                                 int n) {
    int wid = (blockIdx.x * blockDim.x + threadIdx.x) >> 6;
    if (wid >= n) return;
    int lane = threadIdx.x & 63, half = lane >> 5, l32 = lane & 31;
    int beg = rp[wid], end = rp[wid + 1];
    f32x4 acc = {0.f, 0.f, 0.f, 0.f};
    for (int e = beg; e < end; e += 4) {
        int i0 = e + half, i1 = e + 2 + half;
        int i0c = i0 < end ? i0 : beg;
        int i1c = i1 < end ? i1 : beg;
        int u0 = col[i0c], u1 = col[i1c];
        float s0 = i0 < end ? norm[u0] : 0.f;
        float s1 = i1 < end ? norm[u1] : 0.f;
        float4 x0 = hin[(size_t)u0 * 32 + l32];
        float4 x1 = hin[(size_t)u1 * 32 + l32];
        acc.x += x0.x * s0; acc.y += x0.y * s0; acc.z += x0.z * s0; acc.w += x0.w * s0;
        acc.x += x1.x * s1; acc.y += x1.y * s1; acc.z += x1.z * s1; acc.w += x1.w * s1;
    }
    acc.x += __shfl_xor(acc.x, 32);
    acc.y += __shfl_xor(acc.y, 32);
    acc.z += __shfl_xor(acc.z, 32);
    acc.w += __shfl_xor(acc.w, 32);
    if (half == 0) {
        float nv = norm[wid];
        float f = nv * nv;
        float4 o; o.x = acc.x * f; o.y = acc.y * f; o.z = acc.z * f; o.w = acc.w * f;
        hout[(size_t)wid * 32 + l32] = o;
    }
}

// k2 of a pair: y = N * A * z  (no gather scale), emit split bf16 (hi+lo).
__global__ void __launch_bounds__(256) spmm128_b_split(const float4* __restrict__ hin,
                                                       uint2* __restrict__ Hi,
                                                       uint2* __restrict__ Lo,
                                                       const int* __restrict__ rp,
                                                       const int* __restrict__ col,
                                                       const float* __restrict__ norm,
                                                       int n) {
    int wid = (blockIdx.x * blockDim.x + threadIdx.x) >> 6;
    if (wid >= n) return;
    int lane = threadIdx.x & 63, half = lane >> 5, l32 = lane & 31;
    int beg = rp[wid], end = rp[wid + 1];
    f32x4 acc = {0.f, 0.f, 0.f, 0.f};
    for (int e = beg; e < end; e += 4) {
        int i0 = e + half, i1 = e + 2 + half;
        int i0c = i0 < end ? i0 : beg;
        int i1c = i1 < end ? i1 : beg;
        int u0 = col[i0c], u1 = col[i1c];
        float s0 = i0 < end ? 1.f : 0.f;
        float s1 = i1 < end ? 1.f : 0.f;
        float4 x0 = hin[(size_t)u0 * 32 + l32];
        float4 x1 = hin[(size_t)u1 * 32 + l32];
        acc.x += x0.x * s0; acc.y += x0.y * s0; acc.z += x0.z * s0; acc.w += x0.w * s0;
        acc.x += x1.x * s1; acc.y += x1.y * s1; acc.z += x1.z * s1; acc.w += x1.w * s1;
    }
    acc.x += __shfl_xor(acc.x, 32);
    acc.y += __shfl_xor(acc.y, 32);
    acc.z += __shfl_xor(acc.z, 32);
    acc.w += __shfl_xor(acc.w, 32);
    if (half == 0) {
        float nv = norm[wid];
        float v0 = acc.x * nv, v1 = acc.y * nv, v2 = acc.z * nv, v3 = acc.w * nv;
        unsigned short h0 = f2bf(v0), h1 = f2bf(v1), h2 = f2bf(v2), h3 = f2bf(v3);
        unsigned short l0 = f2bf(v0 - bf2f(h0)), l1 = f2bf(v1 - bf2f(h1));
        unsigned short l2 = f2bf(v2 - bf2f(h2)), l3 = f2bf(v3 - bf2f(h3));
        uint2 hp, lp;
        hp.x = (unsigned int)h0 | ((unsigned int)h1 << 16);
        hp.y = (unsigned int)h2 | ((unsigned int)h3 << 16);
        lp.x = (unsigned int)l0 | ((unsigned int)l1 << 16);
        lp.y = (unsigned int)l2 | ((unsigned int)l3 << 16);
        Hi[(size_t)wid * 32 + l32] = hp;
        Lo[(size_t)wid * 32 + l32] = lp;
    }
}

// 40-wide hops (layer 3 after projection). FIRST: gather-scale + nv^2 epi.
template <int FIRST, int BIAS>
__global__ void __launch_bounds__(256) spmm40_kernel(const float* __restrict__ hin,
                                                     float* __restrict__ hout,
                                                     const int* __restrict__ rp,
                                                     const int* __restrict__ col,
                                                     const float* __restrict__ norm,
                                                     const float* __restrict__ b3,
                                                     int n) {
    int wid = (blockIdx.x * blockDim.x + threadIdx.x) >> 6;
    if (wid >= n) return;
    int lane = threadIdx.x & 63;
    int beg = rp[wid], end = rp[wid + 1];
    bool act = lane < 40;
    float acc = 0.f;
    for (int e = beg; e < end; e += 4) {
        #pragma unroll
        for (int j = 0; j < 4; ++j) {
            int i = e + j;
            int ic = i < end ? i : beg;
            int u = col[ic];
            float s = (i < end) ? (FIRST ? norm[u] : 1.f) : 0.f;
            float x = act ? hin[(size_t)u * 40 + lane] : 0.f;
            acc += x * s;
        }
    }
    if (act) {
        float nv = norm[wid];
        float f = FIRST ? nv * nv : nv;
        float v = acc * f;
        if (BIAS) v += b3[lane];
        hout[(size_t)wid * 40 + lane] = v;
    }
}

// ------------------------- W fragment preparation --------------------------
// frag f = ks*CF + cf; element (f, lane, j) = W[k][c],
// k = ks*32 + 8*(lane>>4) + j, c = cf*16 + (lane&15).

__device__ __forceinline__ void wprep_one(const float* __restrict__ W,
                                          short* __restrict__ Wh,
                                          short* __restrict__ Wl,
                                          int ncols, int CF, int i) {
    int j = i & 7;
    int lane = (i >> 3) & 63;
    int f = i >> 9;
    int cf = f % CF, ks = f / CF;
    int k = ks * 32 + 8 * (lane >> 4) + j;
    int c = cf * 16 + (lane & 15);
    float v = (c < ncols) ? W[k * ncols + c] : 0.f;
    unsigned short h = f2bf(v);
    unsigned short l = f2bf(v - bf2f(h));
    Wh[i] = (short)h;
    Wl[i] = (short)l;
}

__global__ void __launch_bounds__(256) wprep_all(const float* __restrict__ W1,
                                                 const float* __restrict__ W2,
                                                 const float* __restrict__ W3,
                                                 short* __restrict__ W1h, short* __restrict__ W1l,
                                                 short* __restrict__ W2h, short* __restrict__ W2l,
                                                 short* __restrict__ W3h, short* __restrict__ W3l) {
    int i = blockIdx.x * blockDim.x + threadIdx.x;
    if (i < 16384) wprep_one(W1, W1h, W1l, 128, 8, i);
    else if (i < 32768) wprep_one(W2, W2h, W2l, 128, 8, i - 16384);
    else if (i < 38912) wprep_one(W3, W3h, W3l, 40, 3, i - 32768);
}

// ------------------------- split-bf16 MFMA GEMMs ---------------------------

template <int MODE>  // 0: f32 out (+bias+relu), 1: split-bf16 out (+bias+relu)
__global__ void __launch_bounds__(256) gemm_mfma128(const unsigned short* __restrict__ Ahi,
                                                    const unsigned short* __restrict__ Alo,
                                                    const short8v* __restrict__ Wh,
                                                    const short8v* __restrict__ Wl,
                                                    const float* __restrict__ bias,
                                                    float* __restrict__ Cf,
                                                    unsigned short* __restrict__ Chi,
                                                    unsigned short* __restrict__ Clo,
                                                    int n) {
    int lane = threadIdx.x & 63;
    int wid = threadIdx.x >> 6;
    int r0 = blockIdx.x * 64 + wid * 16;
    if (r0 >= n) return;
    int arow = r0 + (lane & 15);
    if (arow > n - 1) arow = n - 1;
    int kbase = 8 * (lane >> 4);
    f32x4 acc[8];
    #pragma unroll
    for (int i = 0; i < 8; ++i) acc[i] = (f32x4){0.f, 0.f, 0.f, 0.f};
    #pragma unroll
    for (int ks = 0; ks < 4; ++ks) {
        short8v ah = *(const short8v*)(Ahi + (size_t)arow * 128 + ks * 32 + kbase);
        short8v al = *(const short8v*)(Alo + (size_t)arow * 128 + ks * 32 + kbase);
        #pragma unroll
        for (int cf = 0; cf < 8; ++cf) {
            short8v bh = Wh[(ks * 8 + cf) * 64 + lane];
            short8v bl = Wl[(ks * 8 + cf) * 64 + lane];
            acc[cf] = __builtin_amdgcn_mfma_f32_16x16x32_bf16(ah, bh, acc[cf], 0, 0, 0);
            acc[cf] = __builtin_amdgcn_mfma_f32_16x16x32_bf16(al, bh, acc[cf], 0, 0, 0);
            acc[cf] = __builtin_amdgcn_mfma_f32_16x16x32_bf16(ah, bl, acc[cf], 0, 0, 0);
        }
    }
    int rbase = r0 + (lane >> 4) * 4;
    int c0 = lane & 15;
    #pragma unroll
    for (int cf = 0; cf < 8; ++cf) {
        int colc = cf * 16 + c0;
        float b = bias[colc];
        #pragma unroll
        for (int q = 0; q < 4; ++q) {
            int row = rbase + q;
            if (row >= n) continue;
            float v = fmaxf(acc[cf][q] + b, 0.f);
            if (MODE == 0) {
                Cf[(size_t)row * 128 + colc] = v;
            } else {
                unsigned short h = f2bf(v);
                unsigned short l = f2bf(v - bf2f(h));
                Chi[(size_t)row * 128 + colc] = h;
                Clo[(size_t)row * 128 + colc] = l;
            }
        }
    }
}

__global__ void __launch_bounds__(256) gemm_mfma40(const unsigned short* __restrict__ Ahi,
                                                   const unsigned short* __restrict__ Alo,
                                                   const short8v* __restrict__ Wh,
                                                   const short8v* __restrict__ Wl,
                                                   float* __restrict__ Cf, int n) {
    int lane = threadIdx.x & 63;
    int wid = threadIdx.x >> 6;
    int r0 = blockIdx.x * 64 + wid * 16;
    if (r0 >= n) return;
    int arow = r0 + (lane & 15);
    if (arow > n - 1) arow = n - 1;
    int kbase = 8 * (lane >> 4);
    f32x4 acc[3];
    #pragma unroll
    for (int i = 0; i < 3; ++i) acc[i] = (f32x4){0.f, 0.f, 0.f, 0.f};
    #pragma unroll
    for (int ks = 0; ks < 4; ++ks) {
        short8v ah = *(const short8v*)(Ahi + (size_t)arow * 128 + ks * 32 + kbase);
        short8v al = *(const short8v*)(Alo + (size_t)arow * 128 + ks * 32 + kbase);
        #pragma unroll
        for (int cf = 0; cf < 3; ++cf) {
            short8v bh = Wh[(ks * 3 + cf) * 64 + lane];
            short8v bl = Wl[(ks * 3 + cf) * 64 + lane];
            acc[cf] = __builtin_amdgcn_mfma_f32_16x16x32_bf16(ah, bh, acc[cf], 0, 0, 0);
            acc[cf] = __builtin_amdgcn_mfma_f32_16x16x32_bf16(al, bh, acc[cf], 0, 0, 0);
            acc[cf] = __builtin_amdgcn_mfma_f32_16x16x32_bf16(ah, bl, acc[cf], 0, 0, 0);
        }
    }
    int rbase = r0 + (lane >> 4) * 4;
    int c0 = lane & 15;
    #pragma unroll
    for (int cf = 0; cf < 3; ++cf) {
        int colc = cf * 16 + c0;
        if (colc >= 40) continue;
        #pragma unroll
        for (int q = 0; q < 4; ++q) {
            int row = rbase + q;
            if (row >= n) continue;
            Cf[(size_t)row * 40 + colc] = acc[cf][q];
        }
    }
}

// --------------------------------- launch ----------------------------------

extern "C" void kernel_launch(void* const* d_in, const int* in_sizes, int n_in,
                              void* d_out, int out_size, void* d_ws, size_t ws_size,
                              hipStream_t stream) {
    const float* features = (const float*)d_in[0];
    const int*   src      = (const int*)d_in[1];
    const int*   dst      = (const int*)d_in[2];
    const float* W1 = (const float*)d_in[3];
    const float* b1 = (const float*)d_in[4];
    const float* W2 = (const float*)d_in[5];
    const float* b2 = (const float*)d_in[6];
    const float* W3 = (const float*)d_in[7];
    const float* b3 = (const float*)d_in[8];
    float* out = (float*)d_out;

    const int N = in_sizes[0] / 128;
    const int E = in_sizes[1];

    char* ws = (char*)d_ws;
    size_t off = 0;
    auto alloc = [&](size_t bytes) -> void* {
        void* p = ws + off;
        off += (bytes + 511) & ~(size_t)511;
        return p;
    };
    float*          F1   = (float*)alloc((size_t)N * 128 * sizeof(float));
    float*          F2   = (float*)alloc((size_t)N * 128 * sizeof(float));
    unsigned short* Hi   = (unsigned short*)alloc((size_t)N * 128 * sizeof(unsigned short));
    unsigned short* Lo   = (unsigned short*)alloc((size_t)N * 128 * sizeof(unsigned short));
    int*   col    = (int*)alloc((size_t)E * sizeof(int));
    int*   deg    = (int*)alloc((size_t)N * sizeof(int));
    int*   cnt    = (int*)alloc((size_t)N * sizeof(int));
    int*   rowptr = (int*)alloc((size_t)(N + 1) * sizeof(int));
    float* norm   = (float*)alloc((size_t)N * sizeof(float));
    int*   bsum   = (int*)alloc((size_t)(SBLK + 2) * sizeof(int));
    short* W1h = (short*)alloc(16384 * sizeof(short));
    short* W1l = (short*)alloc(16384 * sizeof(short));
    short* W2h = (short*)alloc(16384 * sizeof(short));
    short* W2l = (short*)alloc(16384 * sizeof(short));
    short* W3h = (short*)alloc(6144 * sizeof(short));
    short* W3l = (short*)alloc(6144 * sizeof(short));
    // 40-wide hop buffers alias F2 (dead after hop 3 consumed it)
    float* G40a = (float*)F2;
    float* G40b = (float*)F2 + (size_t)N * 40;

    const int seg = (N + SBLK - 1) / SBLK;

    // --- CSR build ---
    hipMemsetAsync(deg, 0, (size_t)N * sizeof(int), stream);
    deg_kernel<<<1024, 256, 0, stream>>>(dst, deg, E);
    scanA_kernel<<<SBLK, 256, 0, stream>>>(deg, rowptr, bsum, norm, N, seg);
    scanB_kernel<<<1, SBLK, 0, stream>>>(bsum);
    scanC_kernel<<<SBLK, 256, 0, stream>>>(rowptr, bsum, cnt, N, seg);
    fill_kernel<<<1024, 256, 0, stream>>>(src, dst, rowptr, cnt, col, E);

    // --- W fragment prep (one launch for all three) ---
    wprep_all<<<(38912 + 255) / 256, 256, 0, stream>>>(W1, W2, W3, W1h, W1l, W2h, W2l, W3h, W3l);

    const int spmm_blocks = (N * 64 + 255) / 256;  // one wave per node
    const int gemm_blocks = (N + 63) / 64;

    // layer 1: z = N^2 A N x ; y = N A z ; relu(y W1 + b1)
    spmm128_a<<<spmm_blocks, 256, 0, stream>>>((const float4*)features, (float4*)F1, rowptr, col, norm, N);
    spmm128_b_split<<<spmm_blocks, 256, 0, stream>>>((const float4*)F1, (uint2*)Hi, (uint2*)Lo, rowptr, col, norm, N);
    gemm_mfma128<0><<<gemm_blocks, 256, 0, stream>>>(Hi, Lo, (const short8v*)W1h, (const short8v*)W1l, b1, F2, nullptr, nullptr, N);

    // layer 2
    spmm128_a<<<spmm_blocks, 256, 0, stream>>>((const float4*)F2, (float4*)F1, rowptr, col, norm, N);
    spmm128_b_split<<<spmm_blocks, 256, 0, stream>>>((const float4*)F1, (uint2*)Hi, (uint2*)Lo, rowptr, col, norm, N);
    gemm_mfma128<1><<<gemm_blocks, 256, 0, stream>>>(Hi, Lo, (const short8v*)W2h, (const short8v*)W2l, b2, nullptr, Hi, Lo, N);

    // layer 3 (reordered): project 128->40 first, then 2 hops at 40-wide, + b3
    gemm_mfma40<<<gemm_blocks, 256, 0, stream>>>(Hi, Lo, (const short8v*)W3h, (const short8v*)W3l, G40a, N);
    spmm40_kernel<1, 0><<<spmm_blocks, 256, 0, stream>>>(G40a, G40b, rowptr, col, norm, nullptr, N);
    spmm40_kernel<0, 1><<<spmm_blocks, 256, 0, stream>>>(G40b, out, rowptr, col, norm, b3, N);
}

// Round 4
// 857.183 us; speedup vs baseline: 2.2626x; 1.2357x over previous
//
#include <hip/hip_runtime.h>
#include <hip/hip_bf16.h>

// ---------------------------------------------------------------------------
// DeepSGC on MI355X:
//   - CSR build per call (deg atomics, 3-kernel multi-block scan, fill)
//   - hop pairs folded: k1: z = N^2 A (N.x via gather-scale); k2: y = N A z
//   - 128-wide SpMM: half-wave float4 gather, 8-edge unroll (4 pairs in flight)
//   - 40-wide SpMM: 6 edge-slots x 10 lanes x float4, shfl cross-slot reduce
//   - dense layers via 3x bf16 MFMA split-precision (hi+lo)
//   - layer-3 reorder: project 128->40 first, then 2 hops at 40-wide
// ---------------------------------------------------------------------------

typedef __attribute__((ext_vector_type(8))) short short8v;   // 8 x bf16
typedef __attribute__((ext_vector_type(4))) float f32x4;

#define SBLK 128  // scan blocks

__device__ __forceinline__ unsigned short f2bf(float x) {
    unsigned int u = __builtin_bit_cast(unsigned int, x);
    unsigned int r = u + 0x7fffu + ((u >> 16) & 1u);   // RNE
    return (unsigned short)(r >> 16);
}
__device__ __forceinline__ float bf2f(unsigned short h) {
    unsigned int u = ((unsigned int)h) << 16;
    return __builtin_bit_cast(float, u);
}

// ------------------------------- CSR build --------------------------------

__global__ void __launch_bounds__(256) deg_kernel(const int* __restrict__ dst,
                                                  int* __restrict__ deg, int E) {
    int stride = gridDim.x * blockDim.x;
    for (int e = blockIdx.x * blockDim.x + threadIdx.x; e < E; e += stride)
        atomicAdd(&deg[dst[e]], 1);
}

// Per-segment exclusive scan + segment totals + norm computation.
__global__ void __launch_bounds__(256) scanA_kernel(const int* __restrict__ deg,
                                                    int* __restrict__ rowptr,
                                                    int* __restrict__ bsum,
                                                    float* __restrict__ norm,
                                                    int n, int seg) {
    __shared__ int ws[4];
    __shared__ int carry;
    int b = blockIdx.x;
    int start = b * seg;
    int finish = start + seg; if (finish > n) finish = n;
    int t = threadIdx.x, lane = t & 63, w = t >> 6;
    if (t == 0) carry = 0;
    __syncthreads();
    for (int base = start; base < finish; base += 256) {
        int i = base + t;
        int v = 0;
        if (i < finish) {
            v = deg[i];
            norm[i] = rsqrtf((float)(v < 1 ? 1 : v));
        }
        int x = v;
        #pragma unroll
        for (int off = 1; off < 64; off <<= 1) {
            int y = __shfl_up(x, off, 64);
            if (lane >= off) x += y;
        }
        if (lane == 63) ws[w] = x;
        __syncthreads();
        int woff = 0;
        #pragma unroll
        for (int k = 0; k < 4; ++k) if (k < w) woff += ws[k];
        if (i < finish) rowptr[i] = carry + woff + x - v;
        int tot = ws[0] + ws[1] + ws[2] + ws[3];
        __syncthreads();
        if (t == 0) carry += tot;
        __syncthreads();
    }
    if (t == 0) bsum[b] = carry;
}

// Exclusive scan of the SBLK segment totals; bsum[SBLK] = grand total.
__global__ void __launch_bounds__(SBLK) scanB_kernel(int* __restrict__ bsum) {
    __shared__ int tmp[SBLK];
    int t = threadIdx.x;
    int orig = bsum[t];
    tmp[t] = orig;
    __syncthreads();
    for (int off = 1; off < SBLK; off <<= 1) {
        int y = (t >= off) ? tmp[t - off] : 0;
        __syncthreads();
        tmp[t] += y;
        __syncthreads();
    }
    bsum[t] = tmp[t] - orig;
    if (t == SBLK - 1) bsum[SBLK] = tmp[t];
}

// Add segment offsets, zero cnt, write rowptr[n].
__global__ void __launch_bounds__(256) scanC_kernel(int* __restrict__ rowptr,
                                                    const int* __restrict__ bsum,
                                                    int* __restrict__ cnt,
                                                    int n, int seg) {
    int b = blockIdx.x;
    int start = b * seg;
    int finish = start + seg; if (finish > n) finish = n;
    int add = bsum[b];
    for (int i = start + threadIdx.x; i < finish; i += 256) {
        rowptr[i] += add;
        cnt[i] = 0;
    }
    if (b == 0 && threadIdx.x == 0) rowptr[n] = bsum[SBLK];
}

__global__ void __launch_bounds__(256) fill_kernel(const int* __restrict__ src,
                                                   const int* __restrict__ dst,
                                                   const int* __restrict__ row_ptr,
                                                   int* __restrict__ cnt,
                                                   int* __restrict__ col, int E) {
    int stride = gridDim.x * blockDim.x;
    for (int e = blockIdx.x * blockDim.x + threadIdx.x; e < E; e += stride) {
        int d = dst[e];
        int p = row_ptr[d] + atomicAdd(&cnt[d], 1);
        col[p] = src[e];
    }
}

// ------------------------------- SpMM hops --------------------------------
// Half-wave float4 gather: lanes 0-31 handle even edges, 32-63 odd edges.
// Eight edges in flight per iteration (4 independent pairs).

// k1 of a pair: z = N^2 * A * (N . x)   (gather-scale by norm[src], f32 out)
__global__ void __launch_bounds__(256) spmm128_a(const float4* __restrict__ hin,
                                                 float4* __restrict__ hout,
                                                 const int* __restrict__ rp,
                                                 const int* __restrict__ col,
                                                 const float* __restrict__ norm,
                                                 int n) {
    int wid = (blockIdx.x * blockDim.x + threadIdx.x) >> 6;
    if (wid >= n) return;
    int lane = threadIdx.x & 63, half = lane >> 5, l32 = lane & 31;
    int beg = rp[wid], end = rp[wid + 1];
    f32x4 acc = {0.f, 0.f, 0.f, 0.f};
    for (int e = beg; e < end; e += 8) {
        int i0 = e + half, i1 = e + 2 + half, i2 = e + 4 + half, i3 = e + 6 + half;
        int i0c = i0 < end ? i0 : beg;
        int i1c = i1 < end ? i1 : beg;
        int i2c = i2 < end ? i2 : beg;
        int i3c = i3 < end ? i3 : beg;
        int u0 = col[i0c], u1 = col[i1c], u2 = col[i2c], u3 = col[i3c];
        float s0 = i0 < end ? norm[u0] : 0.f;
        float s1 = i1 < end ? norm[u1] : 0.f;
        float s2 = i2 < end ? norm[u2] : 0.f;
        float s3 = i3 < end ? norm[u3] : 0.f;
        float4 x0 = hin[(size_t)u0 * 32 + l32];
        float4 x1 = hin[(size_t)u1 * 32 + l32];
        float4 x2 = hin[(size_t)u2 * 32 + l32];
        float4 x3 = hin[(size_t)u3 * 32 + l32];
        acc.x += x0.x * s0; acc.y += x0.y * s0; acc.z += x0.z * s0; acc.w += x0.w * s0;
        acc.x += x1.x * s1; acc.y += x1.y * s1; acc.z += x1.z * s1; acc.w += x1.w * s1;
        acc.x += x2.x * s2; acc.y += x2.y * s2; acc.z += x2.z * s2; acc.w += x2.w * s2;
        acc.x += x3.x * s3; acc.y += x3.y * s3; acc.z += x3.z * s3; acc.w += x3.w * s3;
    }
    acc.x += __shfl_xor(acc.x, 32);
    acc.y += __shfl_xor(acc.y, 32);
    acc.z += __shfl_xor(acc.z, 32);
    acc.w += __shfl_xor(acc.w, 32);
    if (half == 0) {
        float nv = norm[wid];
        float f = nv * nv;
        float4 o; o.x = acc.x * f; o.y = acc.y * f; o.z = acc.z * f; o.w = acc.w * f;
        hout[(size_t)wid * 32 + l32] = o;
    }
}

// k2 of a pair: y = N * A * z  (no gather scale), emit split bf16 (hi+lo).
__global__ void __launch_bounds__(256) spmm128_b_split(const float4* __restrict__ hin,
                                                       uint2* __restrict__ Hi,
                                                       uint2* __restrict__ Lo,
                                                       const int* __restrict__ rp,
                                                       const int* __restrict__ col,
                                                       const float* __restrict__ norm,
                                                       int n) {
    int wid = (blockIdx.x * blockDim.x + threadIdx.x) >> 6;
    if (wid >= n) return;
    int lane = threadIdx.x & 63, half = lane >> 5, l32 = lane & 31;
    int beg = rp[wid], end = rp[wid + 1];
    f32x4 acc = {0.f, 0.f, 0.f, 0.f};
    for (int e = beg; e < end; e += 8) {
        int i0 = e + half, i1 = e + 2 + half, i2 = e + 4 + half, i3 = e + 6 + half;
        int i0c = i0 < end ? i0 : beg;
        int i1c = i1 < end ? i1 : beg;
        int i2c = i2 < end ? i2 : beg;
        int i3c = i3 < end ? i3 : beg;
        int u0 = col[i0c], u1 = col[i1c], u2 = col[i2c], u3 = col[i3c];
        float s0 = i0 < end ? 1.f : 0.f;
        float s1 = i1 < end ? 1.f : 0.f;
        float s2 = i2 < end ? 1.f : 0.f;
        float s3 = i3 < end ? 1.f : 0.f;
        float4 x0 = hin[(size_t)u0 * 32 + l32];
        float4 x1 = hin[(size_t)u1 * 32 + l32];
        float4 x2 = hin[(size_t)u2 * 32 + l32];
        float4 x3 = hin[(size_t)u3 * 32 + l32];
        acc.x += x0.x * s0; acc.y += x0.y * s0; acc.z += x0.z * s0; acc.w += x0.w * s0;
        acc.x += x1.x * s1; acc.y += x1.y * s1; acc.z += x1.z * s1; acc.w += x1.w * s1;
        acc.x += x2.x * s2; acc.y += x2.y * s2; acc.z += x2.z * s2; acc.w += x2.w * s2;
        acc.x += x3.x * s3; acc.y += x3.y * s3; acc.z += x3.z * s3; acc.w += x3.w * s3;
    }
    acc.x += __shfl_xor(acc.x, 32);
    acc.y += __shfl_xor(acc.y, 32);
    acc.z += __shfl_xor(acc.z, 32);
    acc.w += __shfl_xor(acc.w, 32);
    if (half == 0) {
        float nv = norm[wid];
        float v0 = acc.x * nv, v1 = acc.y * nv, v2 = acc.z * nv, v3 = acc.w * nv;
        unsigned short h0 = f2bf(v0), h1 = f2bf(v1), h2 = f2bf(v2), h3 = f2bf(v3);
        unsigned short l0 = f2bf(v0 - bf2f(h0)), l1 = f2bf(v1 - bf2f(h1));
        unsigned short l2 = f2bf(v2 - bf2f(h2)), l3 = f2bf(v3 - bf2f(h3));
        uint2 hp, lp;
        hp.x = (unsigned int)h0 | ((unsigned int)h1 << 16);
        hp.y = (unsigned int)h2 | ((unsigned int)h3 << 16);
        lp.x = (unsigned int)l0 | ((unsigned int)l1 << 16);
        lp.y = (unsigned int)l2 | ((unsigned int)l3 << 16);
        Hi[(size_t)wid * 32 + l32] = hp;
        Lo[(size_t)wid * 32 + l32] = lp;
    }
}

// 40-wide hops: 6 edge-slots x 10 lanes, each slot gathers a row as float4.
// Unroll 2 -> 12 edges in flight. Cross-slot reduce via bpermute shfl.
template <int FIRST, int BIAS>
__global__ void __launch_bounds__(256) spmm40_kernel(const f32x4* __restrict__ hin,
                                                     f32x4* __restrict__ hout,
                                                     const int* __restrict__ rp,
                                                     const int* __restrict__ col,
                                                     const float* __restrict__ norm,
                                                     const float* __restrict__ b3,
                                                     int n) {
    int wid = (blockIdx.x * blockDim.x + threadIdx.x) >> 6;
    if (wid >= n) return;
    int lane = threadIdx.x & 63;
    int slot = lane / 10;      // 0..5 active edge slots; slot 6 = lanes 60-63 idle
    int t = lane % 10;         // float4 index within the 40-float row
    bool active = slot < 6;
    int beg = rp[wid], end = rp[wid + 1];
    f32x4 acc = {0.f, 0.f, 0.f, 0.f};
    for (int base = beg; base < end; base += 12) {
        int i0 = base + slot, i1 = base + 6 + slot;
        int i0c = (active && i0 < end) ? i0 : beg;
        int i1c = (active && i1 < end) ? i1 : beg;
        int u0 = col[i0c], u1 = col[i1c];
        float s0 = (active && i0 < end) ? (FIRST ? norm[u0] : 1.f) : 0.f;
        float s1 = (active && i1 < end) ? (FIRST ? norm[u1] : 1.f) : 0.f;
        f32x4 x0 = hin[(size_t)u0 * 10 + t];
        f32x4 x1 = hin[(size_t)u1 * 10 + t];
        acc.x += x0.x * s0; acc.y += x0.y * s0; acc.z += x0.z * s0; acc.w += x0.w * s0;
        acc.x += x1.x * s1; acc.y += x1.y * s1; acc.z += x1.z * s1; acc.w += x1.w * s1;
    }
    // total over the 6 slots (read the UNMODIFIED acc; all lanes participate)
    f32x4 tot = acc;
    #pragma unroll
    for (int k = 1; k < 6; ++k) {
        int srcl = (lane % 10) + ((slot + k) % 6) * 10;  // < 60, always valid
        tot.x += __shfl(acc.x, srcl);
        tot.y += __shfl(acc.y, srcl);
        tot.z += __shfl(acc.z, srcl);
        tot.w += __shfl(acc.w, srcl);
    }
    if (slot == 0) {  // lanes 0-9 write the 40-float row
        float nv = norm[wid];
        float f = FIRST ? nv * nv : nv;
        f32x4 o;
        o.x = tot.x * f; o.y = tot.y * f; o.z = tot.z * f; o.w = tot.w * f;
        if (BIAS) {
            f32x4 bv = ((const f32x4*)b3)[t];
            o.x += bv.x; o.y += bv.y; o.z += bv.z; o.w += bv.w;
        }
        hout[(size_t)wid * 10 + t] = o;
    }
}

// ------------------------- W fragment preparation --------------------------
// frag f = ks*CF + cf; element (f, lane, j) = W[k][c],
// k = ks*32 + 8*(lane>>4) + j, c = cf*16 + (lane&15).

__device__ __forceinline__ void wprep_one(const float* __restrict__ W,
                                          short* __restrict__ Wh,
                                          short* __restrict__ Wl,
                                          int ncols, int CF, int i) {
    int j = i & 7;
    int lane = (i >> 3) & 63;
    int f = i >> 9;
    int cf = f % CF, ks = f / CF;
    int k = ks * 32 + 8 * (lane >> 4) + j;
    int c = cf * 16 + (lane & 15);
    float v = (c < ncols) ? W[k * ncols + c] : 0.f;
    unsigned short h = f2bf(v);
    unsigned short l = f2bf(v - bf2f(h));
    Wh[i] = (short)h;
    Wl[i] = (short)l;
}

__global__ void __launch_bounds__(256) wprep_all(const float* __restrict__ W1,
                                                 const float* __restrict__ W2,
                                                 const float* __restrict__ W3,
                                                 short* __restrict__ W1h, short* __restrict__ W1l,
                                                 short* __restrict__ W2h, short* __restrict__ W2l,
                                                 short* __restrict__ W3h, short* __restrict__ W3l) {
    int i = blockIdx.x * blockDim.x + threadIdx.x;
    if (i < 16384) wprep_one(W1, W1h, W1l, 128, 8, i);
    else if (i < 32768) wprep_one(W2, W2h, W2l, 128, 8, i - 16384);
    else if (i < 38912) wprep_one(W3, W3h, W3l, 40, 3, i - 32768);
}

// ------------------------- split-bf16 MFMA GEMMs ---------------------------

template <int MODE>  // 0: f32 out (+bias+relu), 1: split-bf16 out (+bias+relu)
__global__ void __launch_bounds__(256) gemm_mfma128(const unsigned short* __restrict__ Ahi,
                                                    const unsigned short* __restrict__ Alo,
                                                    const short8v* __restrict__ Wh,
                                                    const short8v* __restrict__ Wl,
                                                    const float* __restrict__ bias,
                                                    float* __restrict__ Cf,
                                                    unsigned short* __restrict__ Chi,
                                                    unsigned short* __restrict__ Clo,
                                                    int n) {
    int lane = threadIdx.x & 63;
    int wid = threadIdx.x >> 6;
    int r0 = blockIdx.x * 64 + wid * 16;
    if (r0 >= n) return;
    int arow = r0 + (lane & 15);
    if (arow > n - 1) arow = n - 1;
    int kbase = 8 * (lane >> 4);
    f32x4 acc[8];
    #pragma unroll
    for (int i = 0; i < 8; ++i) acc[i] = (f32x4){0.f, 0.f, 0.f, 0.f};
    #pragma unroll
    for (int ks = 0; ks < 4; ++ks) {
        short8v ah = *(const short8v*)(Ahi + (size_t)arow * 128 + ks * 32 + kbase);
        short8v al = *(const short8v*)(Alo + (size_t)arow * 128 + ks * 32 + kbase);
        #pragma unroll
        for (int cf = 0; cf < 8; ++cf) {
            short8v bh = Wh[(ks * 8 + cf) * 64 + lane];
            short8v bl = Wl[(ks * 8 + cf) * 64 + lane];
            acc[cf] = __builtin_amdgcn_mfma_f32_16x16x32_bf16(ah, bh, acc[cf], 0, 0, 0);
            acc[cf] = __builtin_amdgcn_mfma_f32_16x16x32_bf16(al, bh, acc[cf], 0, 0, 0);
            acc[cf] = __builtin_amdgcn_mfma_f32_16x16x32_bf16(ah, bl, acc[cf], 0, 0, 0);
        }
    }
    int rbase = r0 + (lane >> 4) * 4;
    int c0 = lane & 15;
    #pragma unroll
    for (int cf = 0; cf < 8; ++cf) {
        int colc = cf * 16 + c0;
        float b = bias[colc];
        #pragma unroll
        for (int q = 0; q < 4; ++q) {
            int row = rbase + q;
            if (row >= n) continue;
            float v = fmaxf(acc[cf][q] + b, 0.f);
            if (MODE == 0) {
                Cf[(size_t)row * 128 + colc] = v;
            } else {
                unsigned short h = f2bf(v);
                unsigned short l = f2bf(v - bf2f(h));
                Chi[(size_t)row * 128 + colc] = h;
                Clo[(size_t)row * 128 + colc] = l;
            }
        }
    }
}

__global__ void __launch_bounds__(256) gemm_mfma40(const unsigned short* __restrict__ Ahi,
                                                   const unsigned short* __restrict__ Alo,
                                                   const short8v* __restrict__ Wh,
                                                   const short8v* __restrict__ Wl,
                                                   float* __restrict__ Cf, int n) {
    int lane = threadIdx.x & 63;
    int wid = threadIdx.x >> 6;
    int r0 = blockIdx.x * 64 + wid * 16;
    if (r0 >= n) return;
    int arow = r0 + (lane & 15);
    if (arow > n - 1) arow = n - 1;
    int kbase = 8 * (lane >> 4);
    f32x4 acc[3];
    #pragma unroll
    for (int i = 0; i < 3; ++i) acc[i] = (f32x4){0.f, 0.f, 0.f, 0.f};
    #pragma unroll
    for (int ks = 0; ks < 4; ++ks) {
        short8v ah = *(const short8v*)(Ahi + (size_t)arow * 128 + ks * 32 + kbase);
        short8v al = *(const short8v*)(Alo + (size_t)arow * 128 + ks * 32 + kbase);
        #pragma unroll
        for (int cf = 0; cf < 3; ++cf) {
            short8v bh = Wh[(ks * 3 + cf) * 64 + lane];
            short8v bl = Wl[(ks * 3 + cf) * 64 + lane];
            acc[cf] = __builtin_amdgcn_mfma_f32_16x16x32_bf16(ah, bh, acc[cf], 0, 0, 0);
            acc[cf] = __builtin_amdgcn_mfma_f32_16x16x32_bf16(al, bh, acc[cf], 0, 0, 0);
            acc[cf] = __builtin_amdgcn_mfma_f32_16x16x32_bf16(ah, bl, acc[cf], 0, 0, 0);
        }
    }
    int rbase = r0 + (lane >> 4) * 4;
    int c0 = lane & 15;
    #pragma unroll
    for (int cf = 0; cf < 3; ++cf) {
        int colc = cf * 16 + c0;
        if (colc >= 40) continue;
        #pragma unroll
        for (int q = 0; q < 4; ++q) {
            int row = rbase + q;
            if (row >= n) continue;
            Cf[(size_t)row * 40 + colc] = acc[cf][q];
        }
    }
}

// --------------------------------- launch ----------------------------------

extern "C" void kernel_launch(void* const* d_in, const int* in_sizes, int n_in,
                              void* d_out, int out_size, void* d_ws, size_t ws_size,
                              hipStream_t stream) {
    const float* features = (const float*)d_in[0];
    const int*   src      = (const int*)d_in[1];
    const int*   dst      = (const int*)d_in[2];
    const float* W1 = (const float*)d_in[3];
    const float* b1 = (const float*)d_in[4];
    const float* W2 = (const float*)d_in[5];
    const float* b2 = (const float*)d_in[6];
    const float* W3 = (const float*)d_in[7];
    const float* b3 = (const float*)d_in[8];
    float* out = (float*)d_out;

    const int N = in_sizes[0] / 128;
    const int E = in_sizes[1];

    char* ws = (char*)d_ws;
    size_t off = 0;
    auto alloc = [&](size_t bytes) -> void* {
        void* p = ws + off;
        off += (bytes + 511) & ~(size_t)511;
        return p;
    };
    float*          F1   = (float*)alloc((size_t)N * 128 * sizeof(float));
    float*          F2   = (float*)alloc((size_t)N * 128 * sizeof(float));
    unsigned short* Hi   = (unsigned short*)alloc((size_t)N * 128 * sizeof(unsigned short));
    unsigned short* Lo   = (unsigned short*)alloc((size_t)N * 128 * sizeof(unsigned short));
    int*   col    = (int*)alloc((size_t)E * sizeof(int));
    int*   deg    = (int*)alloc((size_t)N * sizeof(int));
    int*   cnt    = (int*)alloc((size_t)N * sizeof(int));
    int*   rowptr = (int*)alloc((size_t)(N + 1) * sizeof(int));
    float* norm   = (float*)alloc((size_t)N * sizeof(float));
    int*   bsum   = (int*)alloc((size_t)(SBLK + 2) * sizeof(int));
    short* W1h = (short*)alloc(16384 * sizeof(short));
    short* W1l = (short*)alloc(16384 * sizeof(short));
    short* W2h = (short*)alloc(16384 * sizeof(short));
    short* W2l = (short*)alloc(16384 * sizeof(short));
    short* W3h = (short*)alloc(6144 * sizeof(short));
    short* W3l = (short*)alloc(6144 * sizeof(short));
    // 40-wide hop buffers alias F2 (dead after hop 3 consumed it)
    float* G40a = (float*)F2;
    float* G40b = (float*)F2 + (size_t)N * 40;

    const int seg = (N + SBLK - 1) / SBLK;

    // --- CSR build ---
    hipMemsetAsync(deg, 0, (size_t)N * sizeof(int), stream);
    deg_kernel<<<1024, 256, 0, stream>>>(dst, deg, E);
    scanA_kernel<<<SBLK, 256, 0, stream>>>(deg, rowptr, bsum, norm, N, seg);
    scanB_kernel<<<1, SBLK, 0, stream>>>(bsum);
    scanC_kernel<<<SBLK, 256, 0, stream>>>(rowptr, bsum, cnt, N, seg);
    fill_kernel<<<1024, 256, 0, stream>>>(src, dst, rowptr, cnt, col, E);

    // --- W fragment prep (one launch for all three) ---
    wprep_all<<<(38912 + 255) / 256, 256, 0, stream>>>(W1, W2, W3, W1h, W1l, W2h, W2l, W3h, W3l);

    const int spmm_blocks = (N * 64 + 255) / 256;  // one wave per node
    const int gemm_blocks = (N + 63) / 64;

    // layer 1: z = N^2 A N x ; y = N A z ; relu(y W1 + b1)
    spmm128_a<<<spmm_blocks, 256, 0, stream>>>((const float4*)features, (float4*)F1, rowptr, col, norm, N);
    spmm128_b_split<<<spmm_blocks, 256, 0, stream>>>((const float4*)F1, (uint2*)Hi, (uint2*)Lo, rowptr, col, norm, N);
    gemm_mfma128<0><<<gemm_blocks, 256, 0, stream>>>(Hi, Lo, (const short8v*)W1h, (const short8v*)W1l, b1, F2, nullptr, nullptr, N);

    // layer 2
    spmm128_a<<<spmm_blocks, 256, 0, stream>>>((const float4*)F2, (float4*)F1, rowptr, col, norm, N);
    spmm128_b_split<<<spmm_blocks, 256, 0, stream>>>((const float4*)F1, (uint2*)Hi, (uint2*)Lo, rowptr, col, norm, N);
    gemm_mfma128<1><<<gemm_blocks, 256, 0, stream>>>(Hi, Lo, (const short8v*)W2h, (const short8v*)W2l, b2, nullptr, Hi, Lo, N);

    // layer 3 (reordered): project 128->40 first, then 2 hops at 40-wide, + b3
    gemm_mfma40<<<gemm_blocks, 256, 0, stream>>>(Hi, Lo, (const short8v*)W3h, (const short8v*)W3l, G40a, N);
    spmm40_kernel<1, 0><<<spmm_blocks, 256, 0, stream>>>((const f32x4*)G40a, (f32x4*)G40b, rowptr, col, norm, nullptr, N);
    spmm40_kernel<0, 1><<<spmm_blocks, 256, 0, stream>>>((const f32x4*)G40b, (f32x4*)out, rowptr, col, norm, b3, N);
}

// Round 5
// 766.140 us; speedup vs baseline: 2.5315x; 1.1188x over previous
//
#include <hip/hip_runtime.h>
#include <hip/hip_bf16.h>

// ---------------------------------------------------------------------------
// DeepSGC on MI355X:
//   - CSR build per call: rank-recording deg pass (1 thread/edge), 2-kernel
//     scan (segment scan + fused top-scan), atomic-free fill
//   - hop pairs folded: k1: z = N^2 A (N.x via gather-scale); k2: y = N A z
//   - 128-wide SpMM: half-wave float4 gather, 8-edge unroll
//   - 40-wide SpMM: 6 edge-slots x 10 lanes x float4, 18-edge unroll
//   - dense layers via 3x bf16 MFMA split-precision (hi+lo)
//   - layer-3 reorder: project 128->40 first, then 2 hops at 40-wide
// ---------------------------------------------------------------------------

typedef __attribute__((ext_vector_type(8))) short short8v;   // 8 x bf16
typedef __attribute__((ext_vector_type(4))) float f32x4;

#define SBLK 128  // scan segments

__device__ __forceinline__ unsigned short f2bf(float x) {
    unsigned int u = __builtin_bit_cast(unsigned int, x);
    unsigned int r = u + 0x7fffu + ((u >> 16) & 1u);   // RNE
    return (unsigned short)(r >> 16);
}
__device__ __forceinline__ float bf2f(unsigned short h) {
    unsigned int u = ((unsigned int)h) << 16;
    return __builtin_bit_cast(float, u);
}

// ------------------------------- CSR build --------------------------------

// One thread per edge: histogram + per-edge arrival rank (atomic-free fill later).
__global__ void __launch_bounds__(256) deg_rank_kernel(const int* __restrict__ dst,
                                                       int* __restrict__ deg,
                                                       int* __restrict__ rank, int E) {
    int e = blockIdx.x * blockDim.x + threadIdx.x;
    if (e < E) rank[e] = atomicAdd(&deg[dst[e]], 1);
}

// Per-segment exclusive scan + segment totals + norm computation.
__global__ void __launch_bounds__(256) scanA_kernel(const int* __restrict__ deg,
                                                    int* __restrict__ rowptr,
                                                    int* __restrict__ bsum,
                                                    float* __restrict__ norm,
                                                    int n, int seg) {
    __shared__ int ws[4];
    __shared__ int carry;
    int b = blockIdx.x;
    int start = b * seg;
    int finish = start + seg; if (finish > n) finish = n;
    int t = threadIdx.x, lane = t & 63, w = t >> 6;
    if (t == 0) carry = 0;
    __syncthreads();
    for (int base = start; base < finish; base += 256) {
        int i = base + t;
        int v = 0;
        if (i < finish) {
            v = deg[i];
            norm[i] = rsqrtf((float)(v < 1 ? 1 : v));
        }
        int x = v;
        #pragma unroll
        for (int off = 1; off < 64; off <<= 1) {
            int y = __shfl_up(x, off, 64);
            if (lane >= off) x += y;
        }
        if (lane == 63) ws[w] = x;
        __syncthreads();
        int woff = 0;
        #pragma unroll
        for (int k = 0; k < 4; ++k) if (k < w) woff += ws[k];
        if (i < finish) rowptr[i] = carry + woff + x - v;
        int tot = ws[0] + ws[1] + ws[2] + ws[3];
        __syncthreads();
        if (t == 0) carry += tot;
        __syncthreads();
    }
    if (t == 0) bsum[b] = carry;
}

// Fused: every block redundantly scans the SBLK segment totals in LDS,
// then adds its segment offset. Block 0 writes rowptr[n].
__global__ void __launch_bounds__(256) scanC_kernel(int* __restrict__ rowptr,
                                                    const int* __restrict__ bsum,
                                                    int n, int seg) {
    __shared__ int tmp[SBLK + 1];
    int b = blockIdx.x, t = threadIdx.x;
    if (t < SBLK) tmp[t] = bsum[t];
    __syncthreads();
    if (t == 0) {
        int s = 0;
        #pragma unroll 4
        for (int i = 0; i < SBLK; ++i) { int v = tmp[i]; tmp[i] = s; s += v; }
        tmp[SBLK] = s;
    }
    __syncthreads();
    int add = tmp[b];
    int start = b * seg;
    int finish = start + seg; if (finish > n) finish = n;
    for (int i = start + t; i < finish; i += 256) rowptr[i] += add;
    if (b == 0 && t == 0) rowptr[n] = tmp[SBLK];
}

// Atomic-free fill: one thread per edge, position known from rank.
__global__ void __launch_bounds__(256) fill_kernel(const int* __restrict__ src,
                                                   const int* __restrict__ dst,
                                                   const int* __restrict__ rowptr,
                                                   const int* __restrict__ rank,
                                                   int* __restrict__ col, int E) {
    int e = blockIdx.x * blockDim.x + threadIdx.x;
    if (e < E) col[rowptr[dst[e]] + rank[e]] = src[e];
}

// ------------------------------- SpMM hops --------------------------------
// Half-wave float4 gather: lanes 0-31 handle even edges, 32-63 odd edges.
// Eight edges in flight per iteration (4 independent pairs).

// k1 of a pair: z = N^2 * A * (N . x)   (gather-scale by norm[src], f32 out)
__global__ void __launch_bounds__(256) spmm128_a(const float4* __restrict__ hin,
                                                 float4* __restrict__ hout,
                                                 const int* __restrict__ rp,
                                                 const int* __restrict__ col,
                                                 const float* __restrict__ norm,
                                                 int n) {
    int wid = (blockIdx.x * blockDim.x + threadIdx.x) >> 6;
    if (wid >= n) return;
    int lane = threadIdx.x & 63, half = lane >> 5, l32 = lane & 31;
    int beg = rp[wid], end = rp[wid + 1];
    f32x4 acc = {0.f, 0.f, 0.f, 0.f};
    for (int e = beg; e < end; e += 8) {
        int i0 = e + half, i1 = e + 2 + half, i2 = e + 4 + half, i3 = e + 6 + half;
        int i0c = i0 < end ? i0 : beg;
        int i1c = i1 < end ? i1 : beg;
        int i2c = i2 < end ? i2 : beg;
        int i3c = i3 < end ? i3 : beg;
        int u0 = col[i0c], u1 = col[i1c], u2 = col[i2c], u3 = col[i3c];
        float s0 = i0 < end ? norm[u0] : 0.f;
        float s1 = i1 < end ? norm[u1] : 0.f;
        float s2 = i2 < end ? norm[u2] : 0.f;
        float s3 = i3 < end ? norm[u3] : 0.f;
        float4 x0 = hin[(size_t)u0 * 32 + l32];
        float4 x1 = hin[(size_t)u1 * 32 + l32];
        float4 x2 = hin[(size_t)u2 * 32 + l32];
        float4 x3 = hin[(size_t)u3 * 32 + l32];
        acc.x += x0.x * s0; acc.y += x0.y * s0; acc.z += x0.z * s0; acc.w += x0.w * s0;
        acc.x += x1.x * s1; acc.y += x1.y * s1; acc.z += x1.z * s1; acc.w += x1.w * s1;
        acc.x += x2.x * s2; acc.y += x2.y * s2; acc.z += x2.z * s2; acc.w += x2.w * s2;
        acc.x += x3.x * s3; acc.y += x3.y * s3; acc.z += x3.z * s3; acc.w += x3.w * s3;
    }
    acc.x += __shfl_xor(acc.x, 32);
    acc.y += __shfl_xor(acc.y, 32);
    acc.z += __shfl_xor(acc.z, 32);
    acc.w += __shfl_xor(acc.w, 32);
    if (half == 0) {
        float nv = norm[wid];
        float f = nv * nv;
        float4 o; o.x = acc.x * f; o.y = acc.y * f; o.z = acc.z * f; o.w = acc.w * f;
        hout[(size_t)wid * 32 + l32] = o;
    }
}

// k2 of a pair: y = N * A * z  (no gather scale), emit split bf16 (hi+lo).
__global__ void __launch_bounds__(256) spmm128_b_split(const float4* __restrict__ hin,
                                                       uint2* __restrict__ Hi,
                                                       uint2* __restrict__ Lo,
                                                       const int* __restrict__ rp,
                                                       const int* __restrict__ col,
                                                       const float* __restrict__ norm,
                                                       int n) {
    int wid = (blockIdx.x * blockDim.x + threadIdx.x) >> 6;
    if (wid >= n) return;
    int lane = threadIdx.x & 63, half = lane >> 5, l32 = lane & 31;
    int beg = rp[wid], end = rp[wid + 1];
    f32x4 acc = {0.f, 0.f, 0.f, 0.f};
    for (int e = beg; e < end; e += 8) {
        int i0 = e + half, i1 = e + 2 + half, i2 = e + 4 + half, i3 = e + 6 + half;
        int i0c = i0 < end ? i0 : beg;
        int i1c = i1 < end ? i1 : beg;
        int i2c = i2 < end ? i2 : beg;
        int i3c = i3 < end ? i3 : beg;
        int u0 = col[i0c], u1 = col[i1c], u2 = col[i2c], u3 = col[i3c];
        float s0 = i0 < end ? 1.f : 0.f;
        float s1 = i1 < end ? 1.f : 0.f;
        float s2 = i2 < end ? 1.f : 0.f;
        float s3 = i3 < end ? 1.f : 0.f;
        float4 x0 = hin[(size_t)u0 * 32 + l32];
        float4 x1 = hin[(size_t)u1 * 32 + l32];
        float4 x2 = hin[(size_t)u2 * 32 + l32];
        float4 x3 = hin[(size_t)u3 * 32 + l32];
        acc.x += x0.x * s0; acc.y += x0.y * s0; acc.z += x0.z * s0; acc.w += x0.w * s0;
        acc.x += x1.x * s1; acc.y += x1.y * s1; acc.z += x1.z * s1; acc.w += x1.w * s1;
        acc.x += x2.x * s2; acc.y += x2.y * s2; acc.z += x2.z * s2; acc.w += x2.w * s2;
        acc.x += x3.x * s3; acc.y += x3.y * s3; acc.z += x3.z * s3; acc.w += x3.w * s3;
    }
    acc.x += __shfl_xor(acc.x, 32);
    acc.y += __shfl_xor(acc.y, 32);
    acc.z += __shfl_xor(acc.z, 32);
    acc.w += __shfl_xor(acc.w, 32);
    if (half == 0) {
        float nv = norm[wid];
        float v0 = acc.x * nv, v1 = acc.y * nv, v2 = acc.z * nv, v3 = acc.w * nv;
        unsigned short h0 = f2bf(v0), h1 = f2bf(v1), h2 = f2bf(v2), h3 = f2bf(v3);
        unsigned short l0 = f2bf(v0 - bf2f(h0)), l1 = f2bf(v1 - bf2f(h1));
        unsigned short l2 = f2bf(v2 - bf2f(h2)), l3 = f2bf(v3 - bf2f(h3));
        uint2 hp, lp;
        hp.x = (unsigned int)h0 | ((unsigned int)h1 << 16);
        hp.y = (unsigned int)h2 | ((unsigned int)h3 << 16);
        lp.x = (unsigned int)l0 | ((unsigned int)l1 << 16);
        lp.y = (unsigned int)l2 | ((unsigned int)l3 << 16);
        Hi[(size_t)wid * 32 + l32] = hp;
        Lo[(size_t)wid * 32 + l32] = lp;
    }
}

// 40-wide hops: 6 edge-slots x 10 lanes, each slot gathers a row as float4.
// Unroll 3 -> 18 edges in flight. Cross-slot reduce via shfl.
template <int FIRST, int BIAS>
__global__ void __launch_bounds__(256) spmm40_kernel(const f32x4* __restrict__ hin,
                                                     f32x4* __restrict__ hout,
                                                     const int* __restrict__ rp,
                                                     const int* __restrict__ col,
                                                     const float* __restrict__ norm,
                                                     const float* __restrict__ b3,
                                                     int n) {
    int wid = (blockIdx.x * blockDim.x + threadIdx.x) >> 6;
    if (wid >= n) return;
    int lane = threadIdx.x & 63;
    int slot = lane / 10;      // 0..5 active edge slots; lanes 60-63 idle
    int t = lane % 10;         // float4 index within the 40-float row
    bool active = slot < 6;
    int beg = rp[wid], end = rp[wid + 1];
    f32x4 acc = {0.f, 0.f, 0.f, 0.f};
    for (int base = beg; base < end; base += 18) {
        int i0 = base + slot, i1 = base + 6 + slot, i2 = base + 12 + slot;
        int i0c = (active && i0 < end) ? i0 : beg;
        int i1c = (active && i1 < end) ? i1 : beg;
        int i2c = (active && i2 < end) ? i2 : beg;
        int u0 = col[i0c], u1 = col[i1c], u2 = col[i2c];
        float s0 = (active && i0 < end) ? (FIRST ? norm[u0] : 1.f) : 0.f;
        float s1 = (active && i1 < end) ? (FIRST ? norm[u1] : 1.f) : 0.f;
        float s2 = (active && i2 < end) ? (FIRST ? norm[u2] : 1.f) : 0.f;
        f32x4 x0 = hin[(size_t)u0 * 10 + t];
        f32x4 x1 = hin[(size_t)u1 * 10 + t];
        f32x4 x2 = hin[(size_t)u2 * 10 + t];
        acc.x += x0.x * s0; acc.y += x0.y * s0; acc.z += x0.z * s0; acc.w += x0.w * s0;
        acc.x += x1.x * s1; acc.y += x1.y * s1; acc.z += x1.z * s1; acc.w += x1.w * s1;
        acc.x += x2.x * s2; acc.y += x2.y * s2; acc.z += x2.z * s2; acc.w += x2.w * s2;
    }
    // total over the 6 slots (read the UNMODIFIED acc; all lanes participate)
    f32x4 tot = acc;
    #pragma unroll
    for (int k = 1; k < 6; ++k) {
        int srcl = (lane % 10) + ((slot + k) % 6) * 10;  // < 60, always valid
        tot.x += __shfl(acc.x, srcl);
        tot.y += __shfl(acc.y, srcl);
        tot.z += __shfl(acc.z, srcl);
        tot.w += __shfl(acc.w, srcl);
    }
    if (slot == 0) {  // lanes 0-9 write the 40-float row
        float nv = norm[wid];
        float f = FIRST ? nv * nv : nv;
        f32x4 o;
        o.x = tot.x * f; o.y = tot.y * f; o.z = tot.z * f; o.w = tot.w * f;
        if (BIAS) {
            f32x4 bv = ((const f32x4*)b3)[t];
            o.x += bv.x; o.y += bv.y; o.z += bv.z; o.w += bv.w;
        }
        hout[(size_t)wid * 10 + t] = o;
    }
}

// ------------------------- W fragment preparation --------------------------
// frag f = ks*CF + cf; element (f, lane, j) = W[k][c],
// k = ks*32 + 8*(lane>>4) + j, c = cf*16 + (lane&15).

__device__ __forceinline__ void wprep_one(const float* __restrict__ W,
                                          short* __restrict__ Wh,
                                          short* __restrict__ Wl,
                                          int ncols, int CF, int i) {
    int j = i & 7;
    int lane = (i >> 3) & 63;
    int f = i >> 9;
    int cf = f % CF, ks = f / CF;
    int k = ks * 32 + 8 * (lane >> 4) + j;
    int c = cf * 16 + (lane & 15);
    float v = (c < ncols) ? W[k * ncols + c] : 0.f;
    unsigned short h = f2bf(v);
    unsigned short l = f2bf(v - bf2f(h));
    Wh[i] = (short)h;
    Wl[i] = (short)l;
}

__global__ void __launch_bounds__(256) wprep_all(const float* __restrict__ W1,
                                                 const float* __restrict__ W2,
                                                 const float* __restrict__ W3,
                                                 short* __restrict__ W1h, short* __restrict__ W1l,
                                                 short* __restrict__ W2h, short* __restrict__ W2l,
                                                 short* __restrict__ W3h, short* __restrict__ W3l) {
    int i = blockIdx.x * blockDim.x + threadIdx.x;
    if (i < 16384) wprep_one(W1, W1h, W1l, 128, 8, i);
    else if (i < 32768) wprep_one(W2, W2h, W2l, 128, 8, i - 16384);
    else if (i < 38912) wprep_one(W3, W3h, W3l, 40, 3, i - 32768);
}

// ------------------------- split-bf16 MFMA GEMMs ---------------------------

template <int MODE>  // 0: f32 out (+bias+relu), 1: split-bf16 out (+bias+relu)
__global__ void __launch_bounds__(256) gemm_mfma128(const unsigned short* __restrict__ Ahi,
                                                    const unsigned short* __restrict__ Alo,
                                                    const short8v* __restrict__ Wh,
                                                    const short8v* __restrict__ Wl,
                                                    const float* __restrict__ bias,
                                                    float* __restrict__ Cf,
                                                    unsigned short* __restrict__ Chi,
                                                    unsigned short* __restrict__ Clo,
                                                    int n) {
    int lane = threadIdx.x & 63;
    int wid = threadIdx.x >> 6;
    int r0 = blockIdx.x * 64 + wid * 16;
    if (r0 >= n) return;
    int arow = r0 + (lane & 15);
    if (arow > n - 1) arow = n - 1;
    int kbase = 8 * (lane >> 4);
    f32x4 acc[8];
    #pragma unroll
    for (int i = 0; i < 8; ++i) acc[i] = (f32x4){0.f, 0.f, 0.f, 0.f};
    #pragma unroll
    for (int ks = 0; ks < 4; ++ks) {
        short8v ah = *(const short8v*)(Ahi + (size_t)arow * 128 + ks * 32 + kbase);
        short8v al = *(const short8v*)(Alo + (size_t)arow * 128 + ks * 32 + kbase);
        #pragma unroll
        for (int cf = 0; cf < 8; ++cf) {
            short8v bh = Wh[(ks * 8 + cf) * 64 + lane];
            short8v bl = Wl[(ks * 8 + cf) * 64 + lane];
            acc[cf] = __builtin_amdgcn_mfma_f32_16x16x32_bf16(ah, bh, acc[cf], 0, 0, 0);
            acc[cf] = __builtin_amdgcn_mfma_f32_16x16x32_bf16(al, bh, acc[cf], 0, 0, 0);
            acc[cf] = __builtin_amdgcn_mfma_f32_16x16x32_bf16(ah, bl, acc[cf], 0, 0, 0);
        }
    }
    int rbase = r0 + (lane >> 4) * 4;
    int c0 = lane & 15;
    #pragma unroll
    for (int cf = 0; cf < 8; ++cf) {
        int colc = cf * 16 + c0;
        float b = bias[colc];
        #pragma unroll
        for (int q = 0; q < 4; ++q) {
            int row = rbase + q;
            if (row >= n) continue;
            float v = fmaxf(acc[cf][q] + b, 0.f);
            if (MODE == 0) {
                Cf[(size_t)row * 128 + colc] = v;
            } else {
                unsigned short h = f2bf(v);
                unsigned short l = f2bf(v - bf2f(h));
                Chi[(size_t)row * 128 + colc] = h;
                Clo[(size_t)row * 128 + colc] = l;
            }
        }
    }
}

__global__ void __launch_bounds__(256) gemm_mfma40(const unsigned short* __restrict__ Ahi,
                                                   const unsigned short* __restrict__ Alo,
                                                   const short8v* __restrict__ Wh,
                                                   const short8v* __restrict__ Wl,
                                                   float* __restrict__ Cf, int n) {
    int lane = threadIdx.x & 63;
    int wid = threadIdx.x >> 6;
    int r0 = blockIdx.x * 64 + wid * 16;
    if (r0 >= n) return;
    int arow = r0 + (lane & 15);
    if (arow > n - 1) arow = n - 1;
    int kbase = 8 * (lane >> 4);
    f32x4 acc[3];
    #pragma unroll
    for (int i = 0; i < 3; ++i) acc[i] = (f32x4){0.f, 0.f, 0.f, 0.f};
    #pragma unroll
    for (int ks = 0; ks < 4; ++ks) {
        short8v ah = *(const short8v*)(Ahi + (size_t)arow * 128 + ks * 32 + kbase);
        short8v al = *(const short8v*)(Alo + (size_t)arow * 128 + ks * 32 + kbase);
        #pragma unroll
        for (int cf = 0; cf < 3; ++cf) {
            short8v bh = Wh[(ks * 3 + cf) * 64 + lane];
            short8v bl = Wl[(ks * 3 + cf) * 64 + lane];
            acc[cf] = __builtin_amdgcn_mfma_f32_16x16x32_bf16(ah, bh, acc[cf], 0, 0, 0);
            acc[cf] = __builtin_amdgcn_mfma_f32_16x16x32_bf16(al, bh, acc[cf], 0, 0, 0);
            acc[cf] = __builtin_amdgcn_mfma_f32_16x16x32_bf16(ah, bl, acc[cf], 0, 0, 0);
        }
    }
    int rbase = r0 + (lane >> 4) * 4;
    int c0 = lane & 15;
    #pragma unroll
    for (int cf = 0; cf < 3; ++cf) {
        int colc = cf * 16 + c0;
        if (colc >= 40) continue;
        #pragma unroll
        for (int q = 0; q < 4; ++q) {
            int row = rbase + q;
            if (row >= n) continue;
            Cf[(size_t)row * 40 + colc] = acc[cf][q];
        }
    }
}

// --------------------------------- launch ----------------------------------

extern "C" void kernel_launch(void* const* d_in, const int* in_sizes, int n_in,
                              void* d_out, int out_size, void* d_ws, size_t ws_size,
                              hipStream_t stream) {
    const float* features = (const float*)d_in[0];
    const int*   src      = (const int*)d_in[1];
    const int*   dst      = (const int*)d_in[2];
    const float* W1 = (const float*)d_in[3];
    const float* b1 = (const float*)d_in[4];
    const float* W2 = (const float*)d_in[5];
    const float* b2 = (const float*)d_in[6];
    const float* W3 = (const float*)d_in[7];
    const float* b3 = (const float*)d_in[8];
    float* out = (float*)d_out;

    const int N = in_sizes[0] / 128;
    const int E = in_sizes[1];

    char* ws = (char*)d_ws;
    size_t off = 0;
    auto alloc = [&](size_t bytes) -> void* {
        void* p = ws + off;
        off += (bytes + 511) & ~(size_t)511;
        return p;
    };
    float*          F1   = (float*)alloc((size_t)N * 128 * sizeof(float));
    float*          F2   = (float*)alloc((size_t)N * 128 * sizeof(float));
    unsigned short* Hi   = (unsigned short*)alloc((size_t)N * 128 * sizeof(unsigned short));
    unsigned short* Lo   = (unsigned short*)alloc((size_t)N * 128 * sizeof(unsigned short));
    int*   col    = (int*)alloc((size_t)E * sizeof(int));
    int*   deg    = (int*)alloc((size_t)N * sizeof(int));
    int*   rowptr = (int*)alloc((size_t)(N + 1) * sizeof(int));
    float* norm   = (float*)alloc((size_t)N * sizeof(float));
    int*   bsum   = (int*)alloc((size_t)(SBLK + 2) * sizeof(int));
    short* W1h = (short*)alloc(16384 * sizeof(short));
    short* W1l = (short*)alloc(16384 * sizeof(short));
    short* W2h = (short*)alloc(16384 * sizeof(short));
    short* W2l = (short*)alloc(16384 * sizeof(short));
    short* W3h = (short*)alloc(6144 * sizeof(short));
    short* W3l = (short*)alloc(6144 * sizeof(short));
    // rank aliases F1 (dead until spmm128_a writes it, after fill consumed rank)
    int* rank = (int*)F1;
    // 40-wide hop buffers alias F2 (dead after hop 3 consumed it)
    float* G40a = (float*)F2;
    float* G40b = (float*)F2 + (size_t)N * 40;

    const int seg = (N + SBLK - 1) / SBLK;
    const int eblocks = (E + 255) / 256;

    // --- CSR build ---
    hipMemsetAsync(deg, 0, (size_t)N * sizeof(int), stream);
    deg_rank_kernel<<<eblocks, 256, 0, stream>>>(dst, deg, rank, E);
    scanA_kernel<<<SBLK, 256, 0, stream>>>(deg, rowptr, bsum, norm, N, seg);
    scanC_kernel<<<SBLK, 256, 0, stream>>>(rowptr, bsum, N, seg);
    fill_kernel<<<eblocks, 256, 0, stream>>>(src, dst, rowptr, rank, col, E);

    // --- W fragment prep (one launch for all three) ---
    wprep_all<<<(38912 + 255) / 256, 256, 0, stream>>>(W1, W2, W3, W1h, W1l, W2h, W2l, W3h, W3l);

    const int spmm_blocks = (N * 64 + 255) / 256;  // one wave per node
    const int gemm_blocks = (N + 63) / 64;

    // layer 1: z = N^2 A N x ; y = N A z ; relu(y W1 + b1)
    spmm128_a<<<spmm_blocks, 256, 0, stream>>>((const float4*)features, (float4*)F1, rowptr, col, norm, N);
    spmm128_b_split<<<spmm_blocks, 256, 0, stream>>>((const float4*)F1, (uint2*)Hi, (uint2*)Lo, rowptr, col, norm, N);
    gemm_mfma128<0><<<gemm_blocks, 256, 0, stream>>>(Hi, Lo, (const short8v*)W1h, (const short8v*)W1l, b1, F2, nullptr, nullptr, N);

    // layer 2
    spmm128_a<<<spmm_blocks, 256, 0, stream>>>((const float4*)F2, (float4*)F1, rowptr, col, norm, N);
    spmm128_b_split<<<spmm_blocks, 256, 0, stream>>>((const float4*)F1, (uint2*)Hi, (uint2*)Lo, rowptr, col, norm, N);
    gemm_mfma128<1><<<gemm_blocks, 256, 0, stream>>>(Hi, Lo, (const short8v*)W2h, (const short8v*)W2l, b2, nullptr, Hi, Lo, N);

    // layer 3 (reordered): project 128->40 first, then 2 hops at 40-wide, + b3
    gemm_mfma40<<<gemm_blocks, 256, 0, stream>>>(Hi, Lo, (const short8v*)W3h, (const short8v*)W3l, G40a, N);
    spmm40_kernel<1, 0><<<spmm_blocks, 256, 0, stream>>>((const f32x4*)G40a, (f32x4*)G40b, rowptr, col, norm, nullptr, N);
    spmm40_kernel<0, 1><<<spmm_blocks, 256, 0, stream>>>((const f32x4*)G40b, (f32x4*)out, rowptr, col, norm, b3, N);
}